// Round 1
// baseline (1160.888 us; speedup 1.0000x reference)
//
#include <hip/hip_runtime.h>
#include <hip/hip_bf16.h>
#include <math.h>

#define B_   4
#define L_   1024
#define H_   768
#define NH_  12
#define E_   24
#define M_   4
#define P_   552
#define NL_  97
#define BLK_ 64
#define H2_  1536          // 2*H
#define HB_  49152         // H*BLK
#define R_   2208          // B*P
#define RT_  35            // ceil(R/64)
#define PR_  2240          // RT_*64
#define NEG_ (-1e30f)

// ---------------- K1: entity_embs = logsumexp over mentions ----------------
__global__ void k_ent_emb(const float* __restrict__ seq, const int* __restrict__ midx,
                          const float* __restrict__ mmask, float* __restrict__ out) {
    int be = blockIdx.x;            // b*E+e
    int b  = be / E_;
    int idx[M_]; float msk[M_];
#pragma unroll
    for (int m = 0; m < M_; ++m) { idx[m] = midx[be*M_+m]; msk[m] = mmask[be*M_+m]; }
    for (int d = threadIdx.x; d < H_; d += blockDim.x) {
        float v[M_]; float mx = NEG_;
#pragma unroll
        for (int m = 0; m < M_; ++m) {
            v[m] = (msk[m] > 0.f) ? seq[(b*L_ + idx[m])*H_ + d] : NEG_;
            mx = fmaxf(mx, v[m]);
        }
        float s = 0.f;
#pragma unroll
        for (int m = 0; m < M_; ++m) s += expf(v[m] - mx);
        out[be*H_ + d] = mx + logf(s);
    }
}

// ---------------- K2: entity_atts = mask-avg of gathered attention rows ----
__global__ void k_ent_att(const float* __restrict__ att, const int* __restrict__ midx,
                          const float* __restrict__ mmask, float* __restrict__ out) {
    int blk = blockIdx.x;           // (b*E+e)*NH + n
    int n  = blk % NH_;
    int be = blk / NH_;
    int b  = be / E_;
    int idx[M_]; float msk[M_]; float denom = 0.f;
#pragma unroll
    for (int m = 0; m < M_; ++m) { idx[m] = midx[be*M_+m]; msk[m] = mmask[be*M_+m]; denom += msk[m]; }
    float inv = 1.f / denom;
    const float* abase = att + (size_t)(b*NH_ + n) * L_ * L_;
    for (int l = threadIdx.x; l < L_; l += blockDim.x) {
        float s = 0.f;
#pragma unroll
        for (int m = 0; m < M_; ++m) s += msk[m] * abase[idx[m]*L_ + l];
        out[(size_t)(be*NH_ + n)*L_ + l] = s * inv;
    }
}

// ---------------- K3: ht_att = normalized mean_n(h_att*t_att) --------------
__global__ void k_ht_att(const float* __restrict__ ea, const int* __restrict__ hts,
                         float* __restrict__ out) {
    __shared__ float buf[L_];
    __shared__ float red[8];
    int bp = blockIdx.x;            // b*P+p
    int b  = bp / P_;
    int h = hts[bp*2+0], t = hts[bp*2+1];
    const float* eh = ea + (size_t)(b*E_ + h)*NH_*L_;
    const float* et = ea + (size_t)(b*E_ + t)*NH_*L_;
    float local = 0.f;
    for (int l = threadIdx.x; l < L_; l += blockDim.x) {
        float s = 0.f;
#pragma unroll
        for (int n = 0; n < NH_; ++n) s += eh[n*L_+l] * et[n*L_+l];
        s *= (1.f/NH_);
        buf[l] = s;
        local += s;
    }
#pragma unroll
    for (int o = 32; o > 0; o >>= 1) local += __shfl_down(local, o);
    int wid = threadIdx.x >> 6, lane = threadIdx.x & 63;
    if (lane == 0) red[wid] = local;
    __syncthreads();
    if (threadIdx.x == 0) red[0] = 1.f / (red[0]+red[1]+red[2]+red[3] + 1e-5f);
    __syncthreads();
    float inv = red[0];
    for (int l = threadIdx.x; l < L_; l += blockDim.x)
        out[(size_t)bp*L_ + l] = buf[l] * inv;
}

// ---------------- K4: rs[b,p,d] = sum_l seq[b,l,d]*ht[b,p,l] ---------------
__global__ void k_rs(const float* __restrict__ seq, const float* __restrict__ ht,
                     float* __restrict__ out) {
    __shared__ float sh[8][L_];     // 32KB
    int b  = blockIdx.y;
    int p0 = blockIdx.x * 8;
    for (int i = threadIdx.x; i < 8*L_; i += blockDim.x)
        sh[i >> 10][i & 1023] = ht[((size_t)(b*P_ + p0) << 10) + i];
    __syncthreads();
    int d = threadIdx.x;
    float acc[8][3] = {};
    const float* sb = seq + (size_t)b*L_*H_;
    for (int l = 0; l < L_; ++l) {
        float s0 = sb[l*H_ + d], s1 = sb[l*H_ + d + 256], s2 = sb[l*H_ + d + 512];
#pragma unroll
        for (int pp = 0; pp < 8; ++pp) {
            float w = sh[pp][l];
            acc[pp][0] += w*s0; acc[pp][1] += w*s1; acc[pp][2] += w*s2;
        }
    }
#pragma unroll
    for (int pp = 0; pp < 8; ++pp) {
        float* o = out + (size_t)(b*P_ + p0 + pp)*H_;
        o[d] = acc[pp][0]; o[d+256] = acc[pp][1]; o[d+512] = acc[pp][2];
    }
}

// ---------------- transpose: dst[c*dstride + r] = src[r*cols + c] ----------
__global__ void k_transpose(const float* __restrict__ src, float* __restrict__ dst,
                            int rows, int cols, int dstride) {
    __shared__ float t[32][33];
    int c0 = blockIdx.x*32, r0 = blockIdx.y*32;
    int lc = threadIdx.x & 31, l4 = threadIdx.x >> 5;
    for (int rr = l4; rr < 32; rr += 8) {
        int r = r0+rr, c = c0+lc;
        t[rr][lc] = (r < rows && c < cols) ? src[(size_t)r*cols + c] : 0.f;
    }
    __syncthreads();
    for (int cc = l4; cc < 32; cc += 8) {
        int c = c0+cc, r = r0+lc;
        if (c < cols && r < dstride) dst[(size_t)c*dstride + r] = t[lc][cc];
    }
}

// ---------------- K5: z = tanh(cat(hs|ts, rs) @ W.T + b) -------------------
template<int WHICH>   // 0 -> zh (hts[...,0], Wh,bh), 1 -> zt
__global__ void k_z(const float* __restrict__ ee, const float* __restrict__ rs,
                    const float* __restrict__ WT, const float* __restrict__ bias,
                    const int* __restrict__ hts, float* __restrict__ out) {
    __shared__ float sh[8][H2_];    // 48KB
    int r0 = blockIdx.x * 8;
    for (int i = threadIdx.x; i < 8*H2_; i += blockDim.x) {
        int row = i / H2_, k = i - row*H2_;
        int r = r0 + row;
        int b = r / P_, p = r - b*P_;
        int eidx = hts[(b*P_+p)*2 + WHICH];
        float v;
        if (k < H_) v = ee[(size_t)(b*E_ + eidx)*H_ + k];
        else        v = rs[(size_t)r*H_ + (k - H_)];
        sh[row][k] = v;
    }
    __syncthreads();
    int d = threadIdx.x;
    float acc[8][3] = {};
    for (int k = 0; k < H2_; ++k) {
        float w0 = WT[(size_t)k*H_ + d], w1 = WT[(size_t)k*H_ + d + 256], w2 = WT[(size_t)k*H_ + d + 512];
#pragma unroll
        for (int row = 0; row < 8; ++row) {
            float c = sh[row][k];
            acc[row][0] += c*w0; acc[row][1] += c*w1; acc[row][2] += c*w2;
        }
    }
    float b0 = bias[d], b1 = bias[d+256], b2 = bias[d+512];
#pragma unroll
    for (int row = 0; row < 8; ++row) {
        float* o = out + (size_t)(r0 + row)*H_;
        o[d]     = tanhf(acc[row][0] + b0);
        o[d+256] = tanhf(acc[row][1] + b1);
        o[d+512] = tanhf(acc[row][2] + b2);
    }
}

// ---------------- K6: logits partials over (rtile, k, ihalf) ---------------
__launch_bounds__(256)
__global__ void k_logits_part(const float* __restrict__ zh, const float* __restrict__ zt,
                              const float* __restrict__ WbT, float* __restrict__ part) {
    __shared__ float shh[64][65];
    __shared__ float sht[64][65];
    int rt = blockIdx.x, k = blockIdx.y, ih = blockIdx.z;
    int r0 = rt * 64;
    for (int i = threadIdx.x; i < 64*64; i += 256) {
        int row = i >> 6, col = i & 63;
        int r = r0 + row;
        float vh = 0.f, vt = 0.f;
        if (r < R_) {
            vh = zh[(size_t)r*H_ + k*64 + col];
            vt = zt[(size_t)r*H_ + k*64 + col];
        }
        shh[row][col] = vh; sht[row][col] = vt;
    }
    __syncthreads();
    int ng = threadIdx.x & 15;      // n = ng*8 .. ng*8+7 (128 padded cols)
    int rg = threadIdx.x >> 4;      // rows rg + 16*m
    float acc[4][8] = {};
    int i0 = ih * 32;
    for (int i = i0; i < i0 + 32; ++i) {
        float ph[4];
#pragma unroll
        for (int m = 0; m < 4; ++m) ph[m] = shh[rg + 16*m][i];
        const float* wrow = WbT + (size_t)((k << 12) + (i << 6)) * 128;
        for (int j = 0; j < 64; ++j) {
            float p[4];
#pragma unroll
            for (int m = 0; m < 4; ++m) p[m] = ph[m] * sht[rg + 16*m][j];
            const float4 w0 = *(const float4*)(wrow + j*128 + ng*8);
            const float4 w1 = *(const float4*)(wrow + j*128 + ng*8 + 4);
#pragma unroll
            for (int m = 0; m < 4; ++m) {
                acc[m][0] += p[m]*w0.x; acc[m][1] += p[m]*w0.y;
                acc[m][2] += p[m]*w0.z; acc[m][3] += p[m]*w0.w;
                acc[m][4] += p[m]*w1.x; acc[m][5] += p[m]*w1.y;
                acc[m][6] += p[m]*w1.z; acc[m][7] += p[m]*w1.w;
            }
        }
    }
    int kz = k*2 + ih;
#pragma unroll
    for (int m = 0; m < 4; ++m) {
        int r = r0 + rg + 16*m;
        if (r < R_) {
            float* o = part + (size_t)(kz*PR_ + r)*128 + ng*8;
#pragma unroll
            for (int c = 0; c < 8; ++c) o[c] = acc[m][c];
        }
    }
}

// ---------------- K7: reduce partials + bias ------------------------------
__global__ void k_logits_reduce(const float* __restrict__ part, const float* __restrict__ bb,
                                float* __restrict__ out) {
    int idx = blockIdx.x*256 + threadIdx.x;
    if (idx >= R_*NL_) return;
    int r = idx / NL_, n = idx - r*NL_;
    float s = bb[n];
#pragma unroll
    for (int kz = 0; kz < 24; ++kz) s += part[(size_t)(kz*PR_ + r)*128 + n];
    out[idx] = s;
}

extern "C" void kernel_launch(void* const* d_in, const int* in_sizes, int n_in,
                              void* d_out, int out_size, void* d_ws, size_t ws_size,
                              hipStream_t stream) {
    const float* seq   = (const float*)d_in[0];
    const float* att   = (const float*)d_in[1];
    const float* mmask = (const float*)d_in[2];
    const float* Wh    = (const float*)d_in[3];
    const float* bh    = (const float*)d_in[4];
    const float* Wt    = (const float*)d_in[5];
    const float* bt    = (const float*)d_in[6];
    const float* Wb    = (const float*)d_in[7];
    const float* bb    = (const float*)d_in[8];
    const int*   midx  = (const int*)d_in[9];
    const int*   hts   = (const int*)d_in[10];
    float* out = (float*)d_out;

    float* ws = (float*)d_ws;
    // layout (floats); part aliases the early intermediates (dead by K6)
    float* zh   = ws;                         // 1,695,744
    float* zt   = zh  + (size_t)R_*H_;        // 1,695,744
    float* WbT  = zt  + (size_t)R_*H_;        // 49152*128 = 6,291,456
    float* WhT  = WbT + (size_t)HB_*128;      // 1,179,648
    float* WtT  = WhT + (size_t)H2_*H_;       // 1,179,648
    float* ee   = WtT + (size_t)H2_*H_;       // 73,728
    float* ea   = ee  + (size_t)B_*E_*H_;     // 1,179,648
    float* ht   = ea  + (size_t)B_*E_*NH_*L_; // 2,260,992
    float* rs   = ht  + (size_t)R_*L_;        // 1,695,744
    float* part = ee;                         // 24*2240*128 = 6,881,280 (aliases ee..rs)

    k_ent_emb<<<dim3(B_*E_), dim3(256), 0, stream>>>(seq, midx, mmask, ee);
    k_ent_att<<<dim3(B_*E_*NH_), dim3(256), 0, stream>>>(att, midx, mmask, ea);
    k_ht_att <<<dim3(R_), dim3(256), 0, stream>>>(ea, hts, ht);

    k_transpose<<<dim3(H2_/32, H_/32), dim3(256), 0, stream>>>(Wh, WhT, H_, H2_, H_);
    k_transpose<<<dim3(H2_/32, H_/32), dim3(256), 0, stream>>>(Wt, WtT, H_, H2_, H_);
    k_transpose<<<dim3(HB_/32, 4),    dim3(256), 0, stream>>>(Wb, WbT, NL_, HB_, 128);

    k_rs<<<dim3(P_/8, B_), dim3(256), 0, stream>>>(seq, ht, rs);

    k_z<0><<<dim3(R_/8), dim3(256), 0, stream>>>(ee, rs, WhT, bh, hts, zh);
    k_z<1><<<dim3(R_/8), dim3(256), 0, stream>>>(ee, rs, WtT, bt, hts, zt);

    k_logits_part<<<dim3(RT_, NH_, 2), dim3(256), 0, stream>>>(zh, zt, WbT, part);
    k_logits_reduce<<<dim3((R_*NL_ + 255)/256), dim3(256), 0, stream>>>(part, bb, out);
}

// Round 2
// 666.798 us; speedup vs baseline: 1.7410x; 1.7410x over previous
//
#include <hip/hip_runtime.h>
#include <hip/hip_bf16.h>
#include <math.h>

#define B_   4
#define L_   1024
#define H_   768
#define NH_  12
#define E_   24
#define M_   4
#define P_   552
#define NL_  97
#define BLK_ 64
#define H2_  1536          // 2*H
#define HB_  49152         // H*BLK
#define R_   2208          // B*P
#define NEG_ (-1e30f)

// logits MFMA tiling
#define RT2_  18           // ceil(R/128)
#define PR2_  2304         // RT2*128
#define S_    24           // K-splits (each 2048)
#define NTIL_ 7            // 112 padded cols / 16
#define KT_   1536         // HB/32 k-steps total

typedef __attribute__((ext_vector_type(8))) short bfrag;
typedef __attribute__((ext_vector_type(4))) float f32x4;

__device__ inline uint pk2(float lo, float hi) {   // trunc-to-bf16 pack
    union { float f; uint u; } a, b; a.f = lo; b.f = hi;
    return (b.u & 0xFFFF0000u) | (a.u >> 16);
}
__device__ inline ushort rne_bf16(float x) {
    union { float f; uint u; } c; c.f = x;
    uint r = c.u + 0x7FFF + ((c.u >> 16) & 1);
    return (ushort)(r >> 16);
}

// ---------------- K1: entity_embs = logsumexp over mentions ----------------
__global__ void k_ent_emb(const float* __restrict__ seq, const int* __restrict__ midx,
                          const float* __restrict__ mmask, float* __restrict__ out) {
    int be = blockIdx.x;            // b*E+e
    int b  = be / E_;
    int idx[M_]; float msk[M_];
#pragma unroll
    for (int m = 0; m < M_; ++m) { idx[m] = midx[be*M_+m]; msk[m] = mmask[be*M_+m]; }
    for (int d = threadIdx.x; d < H_; d += blockDim.x) {
        float v[M_]; float mx = NEG_;
#pragma unroll
        for (int m = 0; m < M_; ++m) {
            v[m] = (msk[m] > 0.f) ? seq[(b*L_ + idx[m])*H_ + d] : NEG_;
            mx = fmaxf(mx, v[m]);
        }
        float s = 0.f;
#pragma unroll
        for (int m = 0; m < M_; ++m) s += expf(v[m] - mx);
        out[be*H_ + d] = mx + logf(s);
    }
}

// ---------------- K2: entity_atts = mask-avg of gathered attention rows ----
__global__ void k_ent_att(const float* __restrict__ att, const int* __restrict__ midx,
                          const float* __restrict__ mmask, float* __restrict__ out) {
    int blk = blockIdx.x;           // (b*E+e)*NH + n
    int n  = blk % NH_;
    int be = blk / NH_;
    int b  = be / E_;
    int idx[M_]; float msk[M_]; float denom = 0.f;
#pragma unroll
    for (int m = 0; m < M_; ++m) { idx[m] = midx[be*M_+m]; msk[m] = mmask[be*M_+m]; denom += msk[m]; }
    float inv = 1.f / denom;
    const float* abase = att + (size_t)(b*NH_ + n) * L_ * L_;
    for (int l = threadIdx.x; l < L_; l += blockDim.x) {
        float s = 0.f;
#pragma unroll
        for (int m = 0; m < M_; ++m) s += msk[m] * abase[idx[m]*L_ + l];
        out[(size_t)(be*NH_ + n)*L_ + l] = s * inv;
    }
}

// ---------------- K3: ht_att = normalized mean_n(h_att*t_att) --------------
__global__ void k_ht_att(const float* __restrict__ ea, const int* __restrict__ hts,
                         float* __restrict__ out) {
    __shared__ float buf[L_];
    __shared__ float red[8];
    int bp = blockIdx.x;            // b*P+p
    int b  = bp / P_;
    int h = hts[bp*2+0], t = hts[bp*2+1];
    const float* eh = ea + (size_t)(b*E_ + h)*NH_*L_;
    const float* et = ea + (size_t)(b*E_ + t)*NH_*L_;
    float local = 0.f;
    for (int l = threadIdx.x; l < L_; l += blockDim.x) {
        float s = 0.f;
#pragma unroll
        for (int n = 0; n < NH_; ++n) s += eh[n*L_+l] * et[n*L_+l];
        s *= (1.f/NH_);
        buf[l] = s;
        local += s;
    }
#pragma unroll
    for (int o = 32; o > 0; o >>= 1) local += __shfl_down(local, o);
    int wid = threadIdx.x >> 6, lane = threadIdx.x & 63;
    if (lane == 0) red[wid] = local;
    __syncthreads();
    if (threadIdx.x == 0) red[0] = 1.f / (red[0]+red[1]+red[2]+red[3] + 1e-5f);
    __syncthreads();
    float inv = red[0];
    for (int l = threadIdx.x; l < L_; l += blockDim.x)
        out[(size_t)bp*L_ + l] = buf[l] * inv;
}

// ---------------- K4: rs[b,p,d] = sum_l seq[b,l,d]*ht[b,p,l] ---------------
// grid (P/8, 3, B); each block does 8 p-rows x 256 d-cols
__global__ void k_rs(const float* __restrict__ seq, const float* __restrict__ ht,
                     float* __restrict__ out) {
    __shared__ float sh[8][L_];     // 32KB
    int b  = blockIdx.z;
    int p0 = blockIdx.x * 8;
    int d  = blockIdx.y * 256 + threadIdx.x;
    for (int i = threadIdx.x; i < 8*L_; i += blockDim.x)
        sh[i >> 10][i & 1023] = ht[((size_t)(b*P_ + p0) << 10) + i];
    __syncthreads();
    float acc[8] = {};
    const float* sb = seq + (size_t)b*L_*H_;
    for (int l = 0; l < L_; ++l) {
        float s0 = sb[l*H_ + d];
#pragma unroll
        for (int pp = 0; pp < 8; ++pp) acc[pp] += sh[pp][l]*s0;
    }
#pragma unroll
    for (int pp = 0; pp < 8; ++pp)
        out[(size_t)(b*P_ + p0 + pp)*H_ + d] = acc[pp];
}

// ---------------- transpose: dst[c*dstride + r] = src[r*cols + c] ----------
__global__ void k_transpose(const float* __restrict__ src, float* __restrict__ dst,
                            int rows, int cols, int dstride) {
    __shared__ float t[32][33];
    int c0 = blockIdx.x*32, r0 = blockIdx.y*32;
    int lc = threadIdx.x & 31, l4 = threadIdx.x >> 5;
    for (int rr = l4; rr < 32; rr += 8) {
        int r = r0+rr, c = c0+lc;
        t[rr][lc] = (r < rows && c < cols) ? src[(size_t)r*cols + c] : 0.f;
    }
    __syncthreads();
    for (int cc = l4; cc < 32; cc += 8) {
        int c = c0+cc, r = r0+lc;
        if (c < cols && r < dstride) dst[(size_t)c*dstride + r] = t[lc][cc];
    }
}

// ---------------- K5: z = tanh(cat(hs|ts, rs) @ W.T + b) -------------------
// grid (R/8, 3): blockIdx.y picks 256-wide d slice
template<int WHICH>   // 0 -> zh (hts[...,0], Wh,bh), 1 -> zt
__global__ void k_z(const float* __restrict__ ee, const float* __restrict__ rs,
                    const float* __restrict__ WT, const float* __restrict__ bias,
                    const int* __restrict__ hts, float* __restrict__ out) {
    __shared__ float sh[8][H2_];    // 48KB
    int r0 = blockIdx.x * 8;
    int d  = blockIdx.y * 256 + threadIdx.x;
    for (int i = threadIdx.x; i < 8*H2_; i += blockDim.x) {
        int row = i / H2_, k = i - row*H2_;
        int r = r0 + row;
        int b = r / P_, p = r - b*P_;
        int eidx = hts[(b*P_+p)*2 + WHICH];
        float v;
        if (k < H_) v = ee[(size_t)(b*E_ + eidx)*H_ + k];
        else        v = rs[(size_t)r*H_ + (k - H_)];
        sh[row][k] = v;
    }
    __syncthreads();
    float acc[8] = {};
    for (int k = 0; k < H2_; ++k) {
        float w0 = WT[(size_t)k*H_ + d];
#pragma unroll
        for (int row = 0; row < 8; ++row) acc[row] += sh[row][k]*w0;
    }
    float b0 = bias[d];
#pragma unroll
    for (int row = 0; row < 8; ++row)
        out[(size_t)(r0 + row)*H_ + d] = tanhf(acc[row] + b0);
}

// ---------------- pack Wb -> bf16 B-fragment layout [kt][nt][lane][8] ------
__global__ void k_wb_pack(const float* __restrict__ Wb, ushort* __restrict__ WbP) {
    int t = blockIdx.x*256 + threadIdx.x;     // over KT_*NTIL_*64
    if (t >= KT_*NTIL_*64) return;
    int lane = t & 63;
    int nt   = (t >> 6) % NTIL_;
    int kt   = t / (NTIL_*64);
    int n = nt*16 + (lane & 15);
    int k = kt*32 + ((lane >> 4) << 3);
    uint w[4];
    if (n < NL_) {
        const float* src = Wb + (size_t)n*HB_ + k;
#pragma unroll
        for (int e = 0; e < 4; ++e)
            w[e] = (uint)rne_bf16(src[2*e]) | ((uint)rne_bf16(src[2*e+1]) << 16);
    } else {
        w[0]=w[1]=w[2]=w[3]=0u;
    }
    *(uint4*)(WbP + (size_t)t*8) = make_uint4(w[0],w[1],w[2],w[3]);
}

// ---------------- K6: logits partials via bf16 MFMA ------------------------
// grid: 432 = RT2_*S_ ; block 256 = 4 waves; BM=128 rows, N=112, K-chunk 2048
__launch_bounds__(256, 2)
__global__ void k_logits_mfma(const float* __restrict__ zh, const float* __restrict__ zt,
                              const ushort* __restrict__ WbP, float* __restrict__ part) {
    __shared__ __align__(16) float zhs[128][33];   // i-slice (32 wide)
    __shared__ __align__(16) float zts[128][68];   // j (64 wide), pad for b128
    int bid = blockIdx.x;
    int rt = bid % RT2_, kc = bid / RT2_;
    int r0 = rt * 128;
    int kblk = kc >> 1, i0 = (kc & 1) * 32;

    for (int t = threadIdx.x; t < 128*32; t += 256) {
        int row = t >> 5, i = t & 31;
        int r = r0 + row;
        zhs[row][i] = (r < R_) ? zh[(size_t)r*H_ + kblk*64 + i0 + i] : 0.f;
    }
    for (int t = threadIdx.x; t < 128*64; t += 256) {
        int row = t >> 6, j = t & 63;
        int r = r0 + row;
        zts[row][j] = (r < R_) ? zt[(size_t)r*H_ + kblk*64 + j] : 0.f;
    }
    __syncthreads();

    int wave = threadIdx.x >> 6, lane = threadIdx.x & 63;
    int rowA0 = wave*32 + (lane & 15);
    int jsub  = (lane >> 4) * 8;

    f32x4 acc[2][NTIL_] = {};
    const ushort* wb0 = WbP + (size_t)(kc*64) * (NTIL_*512) + lane*8;

#pragma unroll 2
    for (int ktl = 0; ktl < 64; ++ktl) {
        const ushort* wp = wb0 + (size_t)ktl * (NTIL_*512);
        bfrag bf[NTIL_];
#pragma unroll
        for (int nt = 0; nt < NTIL_; ++nt)
            bf[nt] = *(const bfrag*)(wp + nt*512);
        int il = ktl >> 1;
        int jb = (ktl & 1) * 32 + jsub;
#pragma unroll
        for (int ms = 0; ms < 2; ++ms) {
            int row = rowA0 + ms*16;
            float h = zhs[row][il];
            float4 t0 = *(const float4*)&zts[row][jb];
            float4 t1 = *(const float4*)&zts[row][jb+4];
            union { uint w[4]; bfrag v; } A;
            A.w[0] = pk2(h*t0.x, h*t0.y);
            A.w[1] = pk2(h*t0.z, h*t0.w);
            A.w[2] = pk2(h*t1.x, h*t1.y);
            A.w[3] = pk2(h*t1.z, h*t1.w);
#pragma unroll
            for (int nt = 0; nt < NTIL_; ++nt)
                acc[ms][nt] = __builtin_amdgcn_mfma_f32_16x16x32_bf16(A.v, bf[nt], acc[ms][nt], 0, 0, 0);
        }
    }

    // C/D layout: col = lane&15, row = (lane>>4)*4 + reg
    int crow0 = wave*32 + (lane >> 4) * 4;
    int ccol  = lane & 15;
#pragma unroll
    for (int ms = 0; ms < 2; ++ms) {
#pragma unroll
        for (int nt = 0; nt < NTIL_; ++nt) {
#pragma unroll
            for (int reg = 0; reg < 4; ++reg) {
                int rp = r0 + crow0 + ms*16 + reg;
                part[((size_t)kc*PR2_ + rp)*112 + nt*16 + ccol] = acc[ms][nt][reg];
            }
        }
    }
}

// ---------------- K7: reduce partials + bias ------------------------------
__global__ void k_logits_reduce(const float* __restrict__ part, const float* __restrict__ bb,
                                float* __restrict__ out) {
    int idx = blockIdx.x*256 + threadIdx.x;
    if (idx >= R_*NL_) return;
    int r = idx / NL_, n = idx - r*NL_;
    float s = bb[n];
#pragma unroll
    for (int kc = 0; kc < S_; ++kc) s += part[((size_t)kc*PR2_ + r)*112 + n];
    out[idx] = s;
}

extern "C" void kernel_launch(void* const* d_in, const int* in_sizes, int n_in,
                              void* d_out, int out_size, void* d_ws, size_t ws_size,
                              hipStream_t stream) {
    const float* seq   = (const float*)d_in[0];
    const float* att   = (const float*)d_in[1];
    const float* mmask = (const float*)d_in[2];
    const float* Wh    = (const float*)d_in[3];
    const float* bh    = (const float*)d_in[4];
    const float* Wt    = (const float*)d_in[5];
    const float* bt    = (const float*)d_in[6];
    const float* Wb    = (const float*)d_in[7];
    const float* bb    = (const float*)d_in[8];
    const int*   midx  = (const int*)d_in[9];
    const int*   hts   = (const int*)d_in[10];
    float* out = (float*)d_out;

    float* ws = (float*)d_ws;
    // layout (float slots)
    float*  zh   = ws;                          // 1,695,744
    float*  zt   = zh + (size_t)R_*H_;          // 1,695,744
    ushort* WbP  = (ushort*)(zt + (size_t)R_*H_); // 5,505,024 ushorts = 2,752,512 slots
    float*  pool = zt + (size_t)R_*H_ + 2752512;
    float*  WhT  = pool;                        // 1,179,648
    float*  WtT  = WhT + (size_t)H2_*H_;        // 1,179,648
    float*  ee   = WtT + (size_t)H2_*H_;        // 73,728
    float*  ea   = ee  + (size_t)B_*E_*H_;      // 1,179,648
    float*  ht   = ea  + (size_t)B_*E_*NH_*L_;  // 2,260,992
    float*  rs   = ht  + (size_t)R_*L_;         // 1,695,744  (pool = 7,569,408)
    float*  part = pool;                        // 24*2304*112 = 6,193,152 (aliases dead pool)

    k_wb_pack<<<dim3((KT_*NTIL_*64 + 255)/256), dim3(256), 0, stream>>>(Wb, WbP);

    k_ent_emb<<<dim3(B_*E_), dim3(256), 0, stream>>>(seq, midx, mmask, ee);
    k_ent_att<<<dim3(B_*E_*NH_), dim3(256), 0, stream>>>(att, midx, mmask, ea);
    k_ht_att <<<dim3(R_), dim3(256), 0, stream>>>(ea, hts, ht);

    k_transpose<<<dim3(H2_/32, H_/32), dim3(256), 0, stream>>>(Wh, WhT, H_, H2_, H_);
    k_transpose<<<dim3(H2_/32, H_/32), dim3(256), 0, stream>>>(Wt, WtT, H_, H2_, H_);

    k_rs<<<dim3(P_/8, 3, B_), dim3(256), 0, stream>>>(seq, ht, rs);

    k_z<0><<<dim3(R_/8, 3), dim3(256), 0, stream>>>(ee, rs, WhT, bh, hts, zh);
    k_z<1><<<dim3(R_/8, 3), dim3(256), 0, stream>>>(ee, rs, WtT, bt, hts, zt);

    k_logits_mfma<<<dim3(RT2_*S_), dim3(256), 0, stream>>>(zh, zt, WbP, part);
    k_logits_reduce<<<dim3((R_*NL_ + 255)/256), dim3(256), 0, stream>>>(part, bb, out);
}

// Round 3
// 244.916 us; speedup vs baseline: 4.7399x; 2.7226x over previous
//
#include <hip/hip_runtime.h>
#include <hip/hip_bf16.h>
#include <math.h>

#define B_   4
#define L_   1024
#define H_   768
#define NH_  12
#define E_   24
#define M_   4
#define P_   552
#define NL_  97
#define BLK_ 64
#define H2_  1536          // 2*H
#define HB_  49152         // H*BLK
#define R_   2208          // B*P
#define NEG_ (-1e30f)

// logits MFMA tiling
#define RT2_  18           // ceil(R/128)
#define PR2_  2304         // RT2*128
#define S_    24           // K-splits (each 2048)
#define NTIL_ 7            // 112 padded cols / 16
#define KT_   1536         // HB/32 k-steps total

typedef __attribute__((ext_vector_type(8))) short bfrag;
typedef __attribute__((ext_vector_type(4))) float f32x4;

__device__ inline uint pk2(float lo, float hi) {   // trunc-to-bf16 pack
    union { float f; uint u; } a, b; a.f = lo; b.f = hi;
    return (b.u & 0xFFFF0000u) | (a.u >> 16);
}
__device__ inline ushort rne_bf16(float x) {
    union { float f; uint u; } c; c.f = x;
    uint r = c.u + 0x7FFF + ((c.u >> 16) & 1);
    return (ushort)(r >> 16);
}
__device__ inline uint rne2(float lo, float hi) {
    return (uint)rne_bf16(lo) | ((uint)rne_bf16(hi) << 16);
}

// ---------------- K1: entity_embs = logsumexp over mentions ----------------
__global__ void k_ent_emb(const float* __restrict__ seq, const int* __restrict__ midx,
                          const float* __restrict__ mmask, float* __restrict__ out) {
    int be = blockIdx.x;            // b*E+e
    int b  = be / E_;
    int idx[M_]; float msk[M_];
#pragma unroll
    for (int m = 0; m < M_; ++m) { idx[m] = midx[be*M_+m]; msk[m] = mmask[be*M_+m]; }
    for (int d = threadIdx.x; d < H_; d += blockDim.x) {
        float v[M_]; float mx = NEG_;
#pragma unroll
        for (int m = 0; m < M_; ++m) {
            v[m] = (msk[m] > 0.f) ? seq[(b*L_ + idx[m])*H_ + d] : NEG_;
            mx = fmaxf(mx, v[m]);
        }
        float s = 0.f;
#pragma unroll
        for (int m = 0; m < M_; ++m) s += expf(v[m] - mx);
        out[be*H_ + d] = mx + logf(s);
    }
}

// ---------------- K2: entity_atts = mask-avg of gathered attention rows ----
__global__ void k_ent_att(const float* __restrict__ att, const int* __restrict__ midx,
                          const float* __restrict__ mmask, float* __restrict__ out) {
    int blk = blockIdx.x;           // (b*E+e)*NH + n
    int n  = blk % NH_;
    int be = blk / NH_;
    int b  = be / E_;
    int idx[M_]; float msk[M_]; float denom = 0.f;
#pragma unroll
    for (int m = 0; m < M_; ++m) { idx[m] = midx[be*M_+m]; msk[m] = mmask[be*M_+m]; denom += msk[m]; }
    float inv = 1.f / denom;
    const float* abase = att + (size_t)(b*NH_ + n) * L_ * L_;
    for (int l = threadIdx.x; l < L_; l += blockDim.x) {
        float s = 0.f;
#pragma unroll
        for (int m = 0; m < M_; ++m) s += msk[m] * abase[idx[m]*L_ + l];
        out[(size_t)(be*NH_ + n)*L_ + l] = s * inv;
    }
}

// ---------------- K3: ht_att = normalized mean_n(h_att*t_att) --------------
__global__ void k_ht_att(const float* __restrict__ ea, const int* __restrict__ hts,
                         float* __restrict__ out) {
    __shared__ float buf[L_];
    __shared__ float red[8];
    int bp = blockIdx.x;            // b*P+p
    int b  = bp / P_;
    int h = hts[bp*2+0], t = hts[bp*2+1];
    const float* eh = ea + (size_t)(b*E_ + h)*NH_*L_;
    const float* et = ea + (size_t)(b*E_ + t)*NH_*L_;
    float local = 0.f;
    for (int l = threadIdx.x; l < L_; l += blockDim.x) {
        float s = 0.f;
#pragma unroll
        for (int n = 0; n < NH_; ++n) s += eh[n*L_+l] * et[n*L_+l];
        s *= (1.f/NH_);
        buf[l] = s;
        local += s;
    }
#pragma unroll
    for (int o = 32; o > 0; o >>= 1) local += __shfl_down(local, o);
    int wid = threadIdx.x >> 6, lane = threadIdx.x & 63;
    if (lane == 0) red[wid] = local;
    __syncthreads();
    if (threadIdx.x == 0) red[0] = 1.f / (red[0]+red[1]+red[2]+red[3] + 1e-5f);
    __syncthreads();
    float inv = red[0];
    for (int l = threadIdx.x; l < L_; l += blockDim.x)
        out[(size_t)bp*L_ + l] = buf[l] * inv;
}

// ---------------- pack W[N][K] f32 -> bf16 fragment layout [kt][nt][lane][8]
__global__ void k_w_pack(const float* __restrict__ W, ushort* __restrict__ WP,
                         int N, int K) {
    int t = blockIdx.x*256 + threadIdx.x;
    int total = (K >> 5) * (N >> 4) * 64;
    if (t >= total) return;
    int lane = t & 63;
    int nt   = (t >> 6) % (N >> 4);
    int kt   = t / ((N >> 4) * 64);
    int n = nt*16 + (lane & 15);
    int k = kt*32 + ((lane >> 4) << 3);
    const float* src = W + (size_t)n*K + k;
    uint w[4];
#pragma unroll
    for (int e = 0; e < 4; ++e) w[e] = rne2(src[2*e], src[2*e+1]);
    *(uint4*)(WP + (size_t)t*8) = make_uint4(w[0],w[1],w[2],w[3]);
}

// ---------------- pack seq[b][l][d] -> per-b fragment layout ---------------
__global__ void k_seq_pack(const float* __restrict__ seq, ushort* __restrict__ out) {
    int t = blockIdx.x*256 + threadIdx.x;     // B*32*48*64
    if (t >= B_*32*48*64) return;
    int lane = t & 63;
    int rest = t >> 6;
    int nt = rest % 48; rest /= 48;
    int kt = rest % 32;
    int b  = rest / 32;
    int n = nt*16 + (lane & 15);
    int k = kt*32 + ((lane >> 4) << 3);
    const float* src = seq + ((size_t)(b*L_ + k))*H_ + n;
    uint w[4];
#pragma unroll
    for (int e = 0; e < 4; ++e) w[e] = rne2(src[(2*e)*H_], src[(2*e+1)*H_]);
    *(uint4*)(out + (size_t)t*8) = make_uint4(w[0],w[1],w[2],w[3]);
}

// ---------------- pack Wb -> bf16 B-fragment layout [kt][nt][lane][8] ------
__global__ void k_wb_pack(const float* __restrict__ Wb, ushort* __restrict__ WbP) {
    int t = blockIdx.x*256 + threadIdx.x;     // over KT_*NTIL_*64
    if (t >= KT_*NTIL_*64) return;
    int lane = t & 63;
    int nt   = (t >> 6) % NTIL_;
    int kt   = t / (NTIL_*64);
    int n = nt*16 + (lane & 15);
    int k = kt*32 + ((lane >> 4) << 3);
    uint w[4];
    if (n < NL_) {
        const float* src = Wb + (size_t)n*HB_ + k;
#pragma unroll
        for (int e = 0; e < 4; ++e) w[e] = rne2(src[2*e], src[2*e+1]);
    } else {
        w[0]=w[1]=w[2]=w[3]=0u;
    }
    *(uint4*)(WbP + (size_t)t*8) = make_uint4(w[0],w[1],w[2],w[3]);
}

// ---------------- K5: z = tanh(cat(hs|ts, rs) @ W.T + b) via MFMA ----------
// grid (35, 12): BM=64, BN=64, K=1536 in 24 chunks of 64
template<int WHICH>
__launch_bounds__(256, 2)
__global__ void k_z_mfma(const float* __restrict__ ee, const float* __restrict__ rs,
                         const ushort* __restrict__ WP, const float* __restrict__ bias,
                         const int* __restrict__ hts, float* __restrict__ out) {
    __shared__ __align__(16) ushort as[64][72];   // 9 KB, row stride 144B
    int r0  = blockIdx.x * 64;
    int nt0 = blockIdx.y * 4;
    int wave = threadIdx.x >> 6, lane = threadIdx.x & 63;

    f32x4 acc[4] = {};
    const ushort* wbase = WP + (size_t)nt0*512 + lane*8;

    for (int kc = 0; kc < 24; ++kc) {
        if (kc) __syncthreads();
        // stage A rows 64 x 64 k-cols, bf16
        for (int t = threadIdx.x; t < 64*8; t += 256) {
            int row = t >> 3, c8 = (t & 7)*8;
            int r = r0 + row;
            int k = kc*64 + c8;
            uint4 w = make_uint4(0,0,0,0);
            if (r < R_) {
                const float* src;
                if (k < H_) {
                    int b = r / P_;
                    int eidx = hts[r*2 + WHICH];
                    src = ee + (size_t)(b*E_ + eidx)*H_ + k;
                } else {
                    src = rs + (size_t)r*H_ + (k - H_);
                }
                float4 f0 = *(const float4*)src;
                float4 f1 = *(const float4*)(src + 4);
                w.x = rne2(f0.x, f0.y); w.y = rne2(f0.z, f0.w);
                w.z = rne2(f1.x, f1.y); w.w = rne2(f1.z, f1.w);
            }
            *(uint4*)&as[row][c8] = w;
        }
        __syncthreads();
#pragma unroll
        for (int kk = 0; kk < 2; ++kk) {
            int kt = kc*2 + kk;
            const ushort* wp = wbase + (size_t)kt*(48*512);
            bfrag bf[4];
#pragma unroll
            for (int j = 0; j < 4; ++j) bf[j] = *(const bfrag*)(wp + j*512);
            int rowA = wave*16 + (lane & 15);
            bfrag af = *(const bfrag*)&as[rowA][kk*32 + ((lane >> 4) << 3)];
#pragma unroll
            for (int j = 0; j < 4; ++j)
                acc[j] = __builtin_amdgcn_mfma_f32_16x16x32_bf16(af, bf[j], acc[j], 0, 0, 0);
        }
    }
    // C layout: col = lane&15, row = (lane>>4)*4 + reg
    int crow = (lane >> 4) * 2 * 2;  // (lane>>4)*4
    int ccol = lane & 15;
#pragma unroll
    for (int j = 0; j < 4; ++j) {
        int n = nt0*16 + j*16 + ccol;
        float bv = bias[n];
#pragma unroll
        for (int reg = 0; reg < 4; ++reg) {
            int r = r0 + wave*16 + crow + reg;
            if (r < R_) out[(size_t)r*H_ + n] = tanhf(acc[j][reg] + bv);
        }
    }
}

// ---------------- K4: rs = ht @ seq via MFMA -------------------------------
// grid (9, 12, B): BM=64 (p rows), BN=64 (d cols), K=1024 in 16 chunks of 64
__launch_bounds__(256, 2)
__global__ void k_rs_mfma(const float* __restrict__ ht, const ushort* __restrict__ seqP,
                          float* __restrict__ out) {
    __shared__ __align__(16) ushort as[64][72];
    int p0  = blockIdx.x * 64;
    int nt0 = blockIdx.y * 4;
    int b   = blockIdx.z;
    int wave = threadIdx.x >> 6, lane = threadIdx.x & 63;

    f32x4 acc[4] = {};
    const ushort* wbase = seqP + ((size_t)b*32*48 + nt0)*512 + lane*8;

    for (int kc = 0; kc < 16; ++kc) {
        if (kc) __syncthreads();
        for (int t = threadIdx.x; t < 64*8; t += 256) {
            int row = t >> 3, c8 = (t & 7)*8;
            int p = p0 + row;
            uint4 w = make_uint4(0,0,0,0);
            if (p < P_) {
                const float* src = ht + ((size_t)(b*P_ + p) << 10) + kc*64 + c8;
                float4 f0 = *(const float4*)src;
                float4 f1 = *(const float4*)(src + 4);
                w.x = rne2(f0.x, f0.y); w.y = rne2(f0.z, f0.w);
                w.z = rne2(f1.x, f1.y); w.w = rne2(f1.z, f1.w);
            }
            *(uint4*)&as[row][c8] = w;
        }
        __syncthreads();
#pragma unroll
        for (int kk = 0; kk < 2; ++kk) {
            int kt = kc*2 + kk;
            const ushort* wp = wbase + (size_t)kt*(48*512);
            bfrag bf[4];
#pragma unroll
            for (int j = 0; j < 4; ++j) bf[j] = *(const bfrag*)(wp + j*512);
            int rowA = wave*16 + (lane & 15);
            bfrag af = *(const bfrag*)&as[rowA][kk*32 + ((lane >> 4) << 3)];
#pragma unroll
            for (int j = 0; j < 4; ++j)
                acc[j] = __builtin_amdgcn_mfma_f32_16x16x32_bf16(af, bf[j], acc[j], 0, 0, 0);
        }
    }
    int crow = (lane >> 4) * 4;
    int ccol = lane & 15;
#pragma unroll
    for (int j = 0; j < 4; ++j) {
        int n = nt0*16 + j*16 + ccol;
#pragma unroll
        for (int reg = 0; reg < 4; ++reg) {
            int p = p0 + wave*16 + crow + reg;
            if (p < P_) out[(size_t)(b*P_ + p)*H_ + n] = acc[j][reg];
        }
    }
}

// ---------------- K6: logits partials via bf16 MFMA ------------------------
// grid: 432 = RT2_*S_ ; block 256 = 4 waves; BM=128 rows, N=112, K-chunk 2048
__launch_bounds__(256, 2)
__global__ void k_logits_mfma(const float* __restrict__ zh, const float* __restrict__ zt,
                              const ushort* __restrict__ WbP, float* __restrict__ part) {
    __shared__ __align__(16) float zhs[128][33];   // i-slice (32 wide)
    __shared__ __align__(16) float zts[128][68];   // j (64 wide), pad for b128
    int bid = blockIdx.x;
    int rt = bid % RT2_, kc = bid / RT2_;
    int r0 = rt * 128;
    int kblk = kc >> 1, i0 = (kc & 1) * 32;

    for (int t = threadIdx.x; t < 128*32; t += 256) {
        int row = t >> 5, i = t & 31;
        int r = r0 + row;
        zhs[row][i] = (r < R_) ? zh[(size_t)r*H_ + kblk*64 + i0 + i] : 0.f;
    }
    for (int t = threadIdx.x; t < 128*64; t += 256) {
        int row = t >> 6, j = t & 63;
        int r = r0 + row;
        zts[row][j] = (r < R_) ? zt[(size_t)r*H_ + kblk*64 + j] : 0.f;
    }
    __syncthreads();

    int wave = threadIdx.x >> 6, lane = threadIdx.x & 63;
    int rowA0 = wave*32 + (lane & 15);
    int jsub  = (lane >> 4) * 8;

    f32x4 acc[2][NTIL_] = {};
    const ushort* wb0 = WbP + (size_t)(kc*64) * (NTIL_*512) + lane*8;

#pragma unroll 2
    for (int ktl = 0; ktl < 64; ++ktl) {
        const ushort* wp = wb0 + (size_t)ktl * (NTIL_*512);
        bfrag bf[NTIL_];
#pragma unroll
        for (int nt = 0; nt < NTIL_; ++nt)
            bf[nt] = *(const bfrag*)(wp + nt*512);
        int il = ktl >> 1;
        int jb = (ktl & 1) * 32 + jsub;
#pragma unroll
        for (int ms = 0; ms < 2; ++ms) {
            int row = rowA0 + ms*16;
            float h = zhs[row][il];
            float4 t0 = *(const float4*)&zts[row][jb];
            float4 t1 = *(const float4*)&zts[row][jb+4];
            union { uint w[4]; bfrag v; } A;
            A.w[0] = pk2(h*t0.x, h*t0.y);
            A.w[1] = pk2(h*t0.z, h*t0.w);
            A.w[2] = pk2(h*t1.x, h*t1.y);
            A.w[3] = pk2(h*t1.z, h*t1.w);
#pragma unroll
            for (int nt = 0; nt < NTIL_; ++nt)
                acc[ms][nt] = __builtin_amdgcn_mfma_f32_16x16x32_bf16(A.v, bf[nt], acc[ms][nt], 0, 0, 0);
        }
    }

    // C/D layout: col = lane&15, row = (lane>>4)*4 + reg
    int crow0 = wave*32 + (lane >> 4) * 4;
    int ccol  = lane & 15;
#pragma unroll
    for (int ms = 0; ms < 2; ++ms) {
#pragma unroll
        for (int nt = 0; nt < NTIL_; ++nt) {
#pragma unroll
            for (int reg = 0; reg < 4; ++reg) {
                int rp = r0 + crow0 + ms*16 + reg;
                part[((size_t)kc*PR2_ + rp)*112 + nt*16 + ccol] = acc[ms][nt][reg];
            }
        }
    }
}

// ---------------- K7: reduce partials + bias ------------------------------
__global__ void k_logits_reduce(const float* __restrict__ part, const float* __restrict__ bb,
                                float* __restrict__ out) {
    int idx = blockIdx.x*256 + threadIdx.x;
    if (idx >= R_*NL_) return;
    int r = idx / NL_, n = idx - r*NL_;
    float s = bb[n];
#pragma unroll
    for (int kc = 0; kc < S_; ++kc) s += part[((size_t)kc*PR2_ + r)*112 + n];
    out[idx] = s;
}

extern "C" void kernel_launch(void* const* d_in, const int* in_sizes, int n_in,
                              void* d_out, int out_size, void* d_ws, size_t ws_size,
                              hipStream_t stream) {
    const float* seq   = (const float*)d_in[0];
    const float* att   = (const float*)d_in[1];
    const float* mmask = (const float*)d_in[2];
    const float* Wh    = (const float*)d_in[3];
    const float* bh    = (const float*)d_in[4];
    const float* Wt    = (const float*)d_in[5];
    const float* bt    = (const float*)d_in[6];
    const float* Wb    = (const float*)d_in[7];
    const float* bb    = (const float*)d_in[8];
    const int*   midx  = (const int*)d_in[9];
    const int*   hts   = (const int*)d_in[10];
    float* out = (float*)d_out;

    float* ws = (float*)d_ws;
    // persistent region (float slots)
    float*  zh   = ws;                             // 1,695,744
    float*  zt   = zh + (size_t)R_*H_;             // 1,695,744
    ushort* WbP  = (ushort*)(zt + (size_t)R_*H_);  // 2,752,512 slots
    ushort* WhP  = (ushort*)((float*)WbP + 2752512);   // 589,824 slots
    ushort* WtP  = (ushort*)((float*)WhP + 589824);    // 589,824 slots
    float*  pool = (float*)WtP + 589824;
    // pool members (all dead by the time `part` is written)
    ushort* seqP = (ushort*)pool;                  // 1,572,864 slots
    float*  ee   = pool + 1572864;                 // 73,728
    float*  ea   = ee  + (size_t)B_*E_*H_;         // 1,179,648
    float*  ht   = ea  + (size_t)B_*E_*NH_*L_;     // 2,260,992
    float*  rs   = ht  + (size_t)R_*L_;            // 1,695,744
    float*  part = pool;                           // 24*2304*112 = 6,193,152 (aliases)

    // packs
    k_wb_pack <<<dim3((KT_*NTIL_*64 + 255)/256), dim3(256), 0, stream>>>(Wb, WbP);
    k_w_pack  <<<dim3((48*48*64 + 255)/256),     dim3(256), 0, stream>>>(Wh, WhP, H_, H2_);
    k_w_pack  <<<dim3((48*48*64 + 255)/256),     dim3(256), 0, stream>>>(Wt, WtP, H_, H2_);
    k_seq_pack<<<dim3((B_*32*48*64 + 255)/256),  dim3(256), 0, stream>>>(seq, seqP);

    // gathers / pooled attention
    k_ent_emb<<<dim3(B_*E_),     dim3(256), 0, stream>>>(seq, midx, mmask, ee);
    k_ent_att<<<dim3(B_*E_*NH_), dim3(256), 0, stream>>>(att, midx, mmask, ea);
    k_ht_att <<<dim3(R_),        dim3(256), 0, stream>>>(ea, hts, ht);

    // rs = ht @ seq  (MFMA)
    k_rs_mfma<<<dim3(9, 12, B_), dim3(256), 0, stream>>>(ht, seqP, rs);

    // zh / zt (MFMA + tanh)
    k_z_mfma<0><<<dim3(35, 12), dim3(256), 0, stream>>>(ee, rs, WhP, bh, hts, zh);
    k_z_mfma<1><<<dim3(35, 12), dim3(256), 0, stream>>>(ee, rs, WtP, bt, hts, zt);

    // logits
    k_logits_mfma  <<<dim3(RT2_*S_), dim3(256), 0, stream>>>(zh, zt, WbP, part);
    k_logits_reduce<<<dim3((R_*NL_ + 255)/256), dim3(256), 0, stream>>>(part, bb, out);
}

// Round 6
// 183.779 us; speedup vs baseline: 6.3168x; 1.3327x over previous
//
#include <hip/hip_runtime.h>
#include <math.h>

#define B_   4
#define L_   1024
#define H_   768
#define NH_  12
#define E_   24
#define M_   4
#define P_   552
#define NL_  97
#define H2_  1536          // 2*H
#define HB_  49152         // H*BLK
#define R_   2208          // B*P
#define NEG_ (-1e30f)

// logits MFMA tiling
#define RT2_  18           // ceil(R/128)
#define PR2_  2304         // RT2*128
#define S_    24           // K-splits (each 2048)
#define NTIL_ 7            // 112 padded cols / 16
#define KT_   1536         // HB/32 k-steps total

typedef _Float16 h2   __attribute__((ext_vector_type(2)));
typedef _Float16 f16x8 __attribute__((ext_vector_type(8)));
typedef float    f32x4 __attribute__((ext_vector_type(4)));

__device__ inline uint pkh(float lo, float hi) {      // fast RTZ pack
    union { __fp16 v __attribute__((ext_vector_type(2))); uint u; } c;
    c.v = __builtin_amdgcn_cvt_pkrtz(lo, hi);
    return c.u;
}
__device__ inline ushort h_rne(float x) {
    union { _Float16 h; ushort u; } c; c.h = (_Float16)x; return c.u;
}
__device__ inline uint h2_rne(float lo, float hi) {
    return (uint)h_rne(lo) | ((uint)h_rne(hi) << 16);
}

// ---------------- fused pack kernel + ent_emb ------------------------------
// block ranges: [0,2688) Wb | [2688,3264) Wh | [3264,3840) Wt |
//               [3840,5376) seq | [5376,5472) ent_emb
// Wh/Wt segments: 48 kt * 48 nt * 64 lanes = 147456 threads = 576 blocks EXACT
#define PKB_WB  2688
#define PKB_W   576
#define PKB_SEQ 1536
#define PKB_EMB 96
__global__ void k_pack(const float* __restrict__ Wb, const float* __restrict__ Wh,
                       const float* __restrict__ Wt, const float* __restrict__ seq,
                       const int* __restrict__ midx, const float* __restrict__ mmask,
                       _Float16* __restrict__ WbP, _Float16* __restrict__ WhP,
                       _Float16* __restrict__ WtP, _Float16* __restrict__ seqP,
                       _Float16* __restrict__ ee) {
    int bid = blockIdx.x;
    if (bid < PKB_WB) {                    // Wb -> [kt][nt][lane][8]
        int t = bid*256 + threadIdx.x;
        int lane = t & 63;
        int nt   = (t >> 6) % NTIL_;
        int kt   = t / (NTIL_*64);
        int n = nt*16 + (lane & 15);
        int k = kt*32 + ((lane >> 4) << 3);
        uint w[4] = {0u,0u,0u,0u};
        if (n < NL_) {
            const float* src = Wb + (size_t)n*HB_ + k;
#pragma unroll
            for (int e = 0; e < 4; ++e) w[e] = h2_rne(src[2*e], src[2*e+1]);
        }
        *(uint4*)(WbP + (size_t)t*8) = make_uint4(w[0],w[1],w[2],w[3]);
        return;
    }
    if (bid < PKB_WB + 2*PKB_W) {          // Wh / Wt -> [kt][nt][lane][8], N=768,K=1536
        int seg = bid - PKB_WB;
        const float* W = (seg < PKB_W) ? Wh : Wt;
        _Float16*   WP = (seg < PKB_W) ? WhP : WtP;
        int t = (seg % PKB_W)*256 + threadIdx.x;
        int lane = t & 63;
        int nt   = (t >> 6) % 48;
        int kt   = t / (48*64);
        int n = nt*16 + (lane & 15);
        int k = kt*32 + ((lane >> 4) << 3);
        const float* src = W + (size_t)n*H2_ + k;
        uint w[4];
#pragma unroll
        for (int e = 0; e < 4; ++e) w[e] = h2_rne(src[2*e], src[2*e+1]);
        *(uint4*)(WP + (size_t)t*8) = make_uint4(w[0],w[1],w[2],w[3]);
        return;
    }
    if (bid < PKB_WB + 2*PKB_W + PKB_SEQ) {    // seq -> per-b fragment layout (B side of rs)
        int t = (bid - PKB_WB - 2*PKB_W)*256 + threadIdx.x;
        int lane = t & 63;
        int rest = t >> 6;
        int nt = rest % 48; rest /= 48;
        int kt = rest % 32;
        int b  = rest / 32;
        int n = nt*16 + (lane & 15);
        int k = kt*32 + ((lane >> 4) << 3);
        const float* src = seq + ((size_t)(b*L_ + k))*H_ + n;
        uint w[4];
#pragma unroll
        for (int e = 0; e < 4; ++e) w[e] = h2_rne(src[(2*e)*H_], src[(2*e+1)*H_]);
        *(uint4*)(seqP + (size_t)t*8) = make_uint4(w[0],w[1],w[2],w[3]);
        return;
    }
    // ent_emb: logsumexp over mentions -> fp16
    int be = bid - (PKB_WB + 2*PKB_W + PKB_SEQ);
    int b  = be / E_;
    int idx[M_]; float msk[M_];
#pragma unroll
    for (int m = 0; m < M_; ++m) { idx[m] = midx[be*M_+m]; msk[m] = mmask[be*M_+m]; }
    for (int d = threadIdx.x; d < H_; d += 256) {
        float v[M_]; float mx = NEG_;
#pragma unroll
        for (int m = 0; m < M_; ++m) {
            v[m] = (msk[m] > 0.f) ? seq[(b*L_ + idx[m])*H_ + d] : NEG_;
            mx = fmaxf(mx, v[m]);
        }
        float s = 0.f;
#pragma unroll
        for (int m = 0; m < M_; ++m) s += expf(v[m] - mx);
        ee[be*H_ + d] = (_Float16)(mx + logf(s));
    }
}

// ---------------- K2: entity_atts (fp16 out) -------------------------------
__global__ void k_ent_att(const float* __restrict__ att, const int* __restrict__ midx,
                          const float* __restrict__ mmask, _Float16* __restrict__ ea) {
    int blk = blockIdx.x;           // (b*E+e)*NH + n
    int n  = blk % NH_;
    int be = blk / NH_;
    int b  = be / E_;
    int idx[M_]; float msk[M_]; float denom = 0.f;
#pragma unroll
    for (int m = 0; m < M_; ++m) { idx[m] = midx[be*M_+m]; msk[m] = mmask[be*M_+m]; denom += msk[m]; }
    float inv = 1.f / denom;
    const float* abase = att + (size_t)(b*NH_ + n) * L_ * L_;
    for (int lp = threadIdx.x; lp < 512; lp += 256) {
        float s0 = 0.f, s1 = 0.f;
#pragma unroll
        for (int m = 0; m < M_; ++m) {
            float2 a = *(const float2*)(abase + idx[m]*L_ + 2*lp);
            s0 += msk[m]*a.x; s1 += msk[m]*a.y;
        }
        *(uint*)(ea + (((size_t)(be*NH_ + n)) << 10) + 2*lp) = pkh(s0*inv, s1*inv);
    }
}

// ---------------- K3: ht_att (fp16 in/out) ---------------------------------
__global__ void k_ht_att(const _Float16* __restrict__ ea, const int* __restrict__ hts,
                         _Float16* __restrict__ ht) {
    __shared__ float buf[L_];
    __shared__ float red[8];
    int bp = blockIdx.x;            // b*P+p
    int b  = bp / P_;
    int h = hts[bp*2+0], t = hts[bp*2+1];
    const h2* eh2 = (const h2*)(ea + ((size_t)(b*E_ + h)*NH_ << 10));
    const h2* et2 = (const h2*)(ea + ((size_t)(b*E_ + t)*NH_ << 10));
    float local = 0.f;
    for (int lp = threadIdx.x; lp < 512; lp += 256) {
        float s0 = 0.f, s1 = 0.f;
#pragma unroll
        for (int n = 0; n < NH_; ++n) {
            h2 a = eh2[n*512 + lp], c = et2[n*512 + lp];
            s0 += (float)a[0]*(float)c[0];
            s1 += (float)a[1]*(float)c[1];
        }
        s0 *= (1.f/NH_); s1 *= (1.f/NH_);
        buf[2*lp] = s0; buf[2*lp+1] = s1;
        local += s0 + s1;
    }
#pragma unroll
    for (int o = 32; o > 0; o >>= 1) local += __shfl_down(local, o);
    int wid = threadIdx.x >> 6, lane = threadIdx.x & 63;
    if (lane == 0) red[wid] = local;
    __syncthreads();
    if (threadIdx.x == 0) red[0] = 1.f / (red[0]+red[1]+red[2]+red[3] + 1e-5f);
    __syncthreads();
    float inv = red[0];
    for (int lp = threadIdx.x; lp < 512; lp += 256)
        *(uint*)(ht + ((size_t)bp << 10) + 2*lp) = pkh(buf[2*lp]*inv, buf[2*lp+1]*inv);
}

// ---------------- K4: rs = ht @ seq via fp16 MFMA --------------------------
// grid (9, 12, B): BM=64 p-rows, BN=64 d-cols, K=1024 in 16 chunks of 64
__launch_bounds__(256, 2)
__global__ void k_rs_mfma(const _Float16* __restrict__ ht, const _Float16* __restrict__ seqP,
                          _Float16* __restrict__ rs) {
    __shared__ _Float16 as[64*72];
    int p0  = blockIdx.x * 64;
    int nt0 = blockIdx.y * 4;
    int b   = blockIdx.z;
    int wave = threadIdx.x >> 6, lane = threadIdx.x & 63;

    f32x4 acc[4] = {};
    const _Float16* wbase = seqP + ((size_t)b*32*48 + nt0)*512 + lane*8;

    for (int kc = 0; kc < 16; ++kc) {
        if (kc) __syncthreads();
        for (int t = threadIdx.x; t < 64*8; t += 256) {
            int row = t >> 3, c8 = (t & 7)*8;
            int p = p0 + row;
            uint4 w = make_uint4(0,0,0,0);
            if (p < P_)
                w = *(const uint4*)(ht + (((size_t)(b*P_ + p)) << 10) + kc*64 + c8);
            *(uint4*)(as + row*72 + c8) = w;
        }
        __syncthreads();
#pragma unroll
        for (int kk = 0; kk < 2; ++kk) {
            int kt = kc*2 + kk;
            const _Float16* wp = wbase + (size_t)kt*(48*512);
            f16x8 bf[4];
#pragma unroll
            for (int j = 0; j < 4; ++j) bf[j] = *(const f16x8*)(wp + j*512);
            int rowA = wave*16 + (lane & 15);
            f16x8 af = *(const f16x8*)(as + rowA*72 + kk*32 + ((lane >> 4) << 3));
#pragma unroll
            for (int j = 0; j < 4; ++j)
                acc[j] = __builtin_amdgcn_mfma_f32_16x16x32_f16(af, bf[j], acc[j], 0, 0, 0);
        }
    }
    int crow = (lane >> 4) * 4;
    int ccol = lane & 15;
#pragma unroll
    for (int j = 0; j < 4; ++j) {
        int n = nt0*16 + j*16 + ccol;
#pragma unroll
        for (int reg = 0; reg < 4; ++reg) {
            int p = p0 + wave*16 + crow + reg;
            if (p < P_) rs[(size_t)(b*P_ + p)*H_ + n] = (_Float16)acc[j][reg];
        }
    }
}

// ---------------- K5: zh & zt via fp16 MFMA (one launch, z = which) --------
// grid (35, 12, 2): BM=64, BN=64, K=1536 in 24 chunks of 64
__launch_bounds__(256, 2)
__global__ void k_z_mfma(const _Float16* __restrict__ ee, const _Float16* __restrict__ rs,
                         const _Float16* __restrict__ WhP, const _Float16* __restrict__ WtP,
                         const float* __restrict__ bh, const float* __restrict__ bt,
                         const int* __restrict__ hts,
                         _Float16* __restrict__ zh, _Float16* __restrict__ zt) {
    __shared__ _Float16 as[64*72];
    int which = blockIdx.z;
    const _Float16* WP  = which ? WtP : WhP;
    const float*    bias = which ? bt  : bh;
    _Float16*       out  = which ? zt  : zh;
    int r0  = blockIdx.x * 64;
    int nt0 = blockIdx.y * 4;
    int wave = threadIdx.x >> 6, lane = threadIdx.x & 63;

    f32x4 acc[4] = {};
    const _Float16* wbase = WP + (size_t)nt0*512 + lane*8;

    for (int kc = 0; kc < 24; ++kc) {
        if (kc) __syncthreads();
        for (int t = threadIdx.x; t < 64*8; t += 256) {
            int row = t >> 3, c8 = (t & 7)*8;
            int r = r0 + row;
            uint4 w = make_uint4(0,0,0,0);
            if (r < R_) {
                if (kc < 12) {
                    int b = r / P_;
                    int eidx = hts[r*2 + which];
                    w = *(const uint4*)(ee + (size_t)(b*E_ + eidx)*H_ + kc*64 + c8);
                } else {
                    w = *(const uint4*)(rs + (size_t)r*H_ + (kc-12)*64 + c8);
                }
            }
            *(uint4*)(as + row*72 + c8) = w;
        }
        __syncthreads();
#pragma unroll
        for (int kk = 0; kk < 2; ++kk) {
            int kt = kc*2 + kk;
            const _Float16* wp = wbase + (size_t)kt*(48*512);
            f16x8 bf[4];
#pragma unroll
            for (int j = 0; j < 4; ++j) bf[j] = *(const f16x8*)(wp + j*512);
            int rowA = wave*16 + (lane & 15);
            f16x8 af = *(const f16x8*)(as + rowA*72 + kk*32 + ((lane >> 4) << 3));
#pragma unroll
            for (int j = 0; j < 4; ++j)
                acc[j] = __builtin_amdgcn_mfma_f32_16x16x32_f16(af, bf[j], acc[j], 0, 0, 0);
        }
    }
    int crow = (lane >> 4) * 4;
    int ccol = lane & 15;
#pragma unroll
    for (int j = 0; j < 4; ++j) {
        int n = nt0*16 + j*16 + ccol;
        float bv = bias[n];
#pragma unroll
        for (int reg = 0; reg < 4; ++reg) {
            int r = r0 + wave*16 + crow + reg;
            if (r < R_) out[(size_t)r*H_ + n] = (_Float16)tanhf(acc[j][reg] + bv);
        }
    }
}

// ---------------- K6: logits partials via fp16 MFMA ------------------------
// grid 432 = RT2_*S_; BM=128, N=112, K-chunk 2048
__launch_bounds__(256, 2)
__global__ void k_logits_mfma(const _Float16* __restrict__ zh, const _Float16* __restrict__ zt,
                              const _Float16* __restrict__ WbP, float* __restrict__ part) {
    __shared__ _Float16 zhs[128*40];   // stride 40 halves (80B)
    __shared__ _Float16 zts[128*72];   // stride 72 halves (144B)
    int bid = blockIdx.x;
    int rt = bid % RT2_, kc = bid / RT2_;
    int r0 = rt * 128;
    int kblk = kc >> 1, i0 = (kc & 1) * 32;

    for (int t = threadIdx.x; t < 128*4; t += 256) {
        int row = t >> 2, i8 = (t & 3)*8;
        int r = r0 + row;
        uint4 w = make_uint4(0,0,0,0);
        if (r < R_) w = *(const uint4*)(zh + (size_t)r*H_ + kblk*64 + i0 + i8);
        *(uint4*)(zhs + row*40 + i8) = w;
    }
    for (int t = threadIdx.x; t < 128*8; t += 256) {
        int row = t >> 3, j8 = (t & 7)*8;
        int r = r0 + row;
        uint4 w = make_uint4(0,0,0,0);
        if (r < R_) w = *(const uint4*)(zt + (size_t)r*H_ + kblk*64 + j8);
        *(uint4*)(zts + row*72 + j8) = w;
    }
    __syncthreads();

    int wave = threadIdx.x >> 6, lane = threadIdx.x & 63;
    int rowA0 = wave*32 + (lane & 15);
    int jsub  = (lane >> 4) * 8;

    f32x4 acc[2][NTIL_] = {};
    const _Float16* wb0 = WbP + (size_t)(kc*64) * (NTIL_*512) + lane*8;

#pragma unroll 2
    for (int ktl = 0; ktl < 64; ++ktl) {
        const _Float16* wp = wb0 + (size_t)ktl * (NTIL_*512);
        f16x8 bf[NTIL_];
#pragma unroll
        for (int nt = 0; nt < NTIL_; ++nt)
            bf[nt] = *(const f16x8*)(wp + nt*512);
        int il = ktl >> 1;
        int jb = (ktl & 1) * 32 + jsub;
#pragma unroll
        for (int ms = 0; ms < 2; ++ms) {
            int row = rowA0 + ms*16;
            _Float16 hv = zhs[row*40 + il];
            h2 hb = {hv, hv};
            union { uint4 u; h2 v[4]; } T;
            T.u = *(const uint4*)(zts + row*72 + jb);
            union { h2 v[4]; f16x8 f; } A;
            A.v[0] = hb * T.v[0];
            A.v[1] = hb * T.v[1];
            A.v[2] = hb * T.v[2];
            A.v[3] = hb * T.v[3];
#pragma unroll
            for (int nt = 0; nt < NTIL_; ++nt)
                acc[ms][nt] = __builtin_amdgcn_mfma_f32_16x16x32_f16(A.f, bf[nt], acc[ms][nt], 0, 0, 0);
        }
    }

    int crow0 = wave*32 + (lane >> 4) * 4;
    int ccol  = lane & 15;
#pragma unroll
    for (int ms = 0; ms < 2; ++ms) {
#pragma unroll
        for (int nt = 0; nt < NTIL_; ++nt) {
#pragma unroll
            for (int reg = 0; reg < 4; ++reg) {
                int rp = r0 + crow0 + ms*16 + reg;
                part[((size_t)kc*PR2_ + rp)*112 + nt*16 + ccol] = acc[ms][nt][reg];
            }
        }
    }
}

// ---------------- K7: reduce partials + bias ------------------------------
__global__ void k_logits_reduce(const float* __restrict__ part, const float* __restrict__ bb,
                                float* __restrict__ out) {
    int idx = blockIdx.x*256 + threadIdx.x;
    if (idx >= R_*NL_) return;
    int r = idx / NL_, n = idx - r*NL_;
    float s = bb[n];
#pragma unroll
    for (int kc = 0; kc < S_; ++kc) s += part[((size_t)kc*PR2_ + r)*112 + n];
    out[idx] = s;
}

extern "C" void kernel_launch(void* const* d_in, const int* in_sizes, int n_in,
                              void* d_out, int out_size, void* d_ws, size_t ws_size,
                              hipStream_t stream) {
    const float* seq   = (const float*)d_in[0];
    const float* att   = (const float*)d_in[1];
    const float* mmask = (const float*)d_in[2];
    const float* Wh    = (const float*)d_in[3];
    const float* bh    = (const float*)d_in[4];
    const float* Wt    = (const float*)d_in[5];
    const float* bt    = (const float*)d_in[6];
    const float* Wb    = (const float*)d_in[7];
    const float* bb    = (const float*)d_in[8];
    const int*   midx  = (const int*)d_in[9];
    const int*   hts   = (const int*)d_in[10];
    float* out = (float*)d_out;

    // workspace carve (no aliasing; ws is ~800MB, we use ~70MB)
    char* base = (char*)d_ws;
    _Float16* WbP  = (_Float16*)base;  base += (size_t)KT_*NTIL_*64*8 * 2;      // 11.0 MB
    _Float16* WhP  = (_Float16*)base;  base += (size_t)48*48*64*8 * 2;          //  2.4 MB
    _Float16* WtP  = (_Float16*)base;  base += (size_t)48*48*64*8 * 2;          //  2.4 MB
    _Float16* seqP = (_Float16*)base;  base += (size_t)B_*32*48*64*8 * 2;       //  6.3 MB
    _Float16* ee   = (_Float16*)base;  base += (size_t)B_*E_*H_ * 2;            //  0.15 MB
    _Float16* ea   = (_Float16*)base;  base += (size_t)B_*E_*NH_*L_ * 2;        //  2.4 MB
    _Float16* ht   = (_Float16*)base;  base += (size_t)R_*L_ * 2;               //  4.5 MB
    _Float16* rs   = (_Float16*)base;  base += (size_t)R_*H_ * 2;               //  3.4 MB
    _Float16* zh   = (_Float16*)base;  base += (size_t)R_*H_ * 2;               //  3.4 MB
    _Float16* zt   = (_Float16*)base;  base += (size_t)R_*H_ * 2;               //  3.4 MB
    float*    part = (float*)base;                                              // 24.8 MB

    k_pack<<<dim3(PKB_WB + 2*PKB_W + PKB_SEQ + PKB_EMB), dim3(256), 0, stream>>>(
        Wb, Wh, Wt, seq, midx, mmask, WbP, WhP, WtP, seqP, ee);

    k_ent_att<<<dim3(B_*E_*NH_), dim3(256), 0, stream>>>(att, midx, mmask, ea);
    k_ht_att <<<dim3(R_),        dim3(256), 0, stream>>>(ea, hts, ht);

    k_rs_mfma<<<dim3(9, 12, B_), dim3(256), 0, stream>>>(ht, seqP, rs);

    k_z_mfma<<<dim3(35, 12, 2), dim3(256), 0, stream>>>(ee, rs, WhP, WtP, bh, bt, hts, zh, zt);

    k_logits_mfma  <<<dim3(RT2_*S_), dim3(256), 0, stream>>>(zh, zt, WbP, part);
    k_logits_reduce<<<dim3((R_*NL_ + 255)/256), dim3(256), 0, stream>>>(part, bb, out);
}

// Round 7
// 152.244 us; speedup vs baseline: 7.6252x; 1.2071x over previous
//
#include <hip/hip_runtime.h>
#include <math.h>

#define B_   4
#define L_   1024
#define H_   768
#define NH_  12
#define E_   24
#define M_   4
#define P_   552
#define NL_  97
#define H2_  1536          // 2*H
#define HB_  49152         // H*BLK
#define R_   2208          // B*P
#define NEG_ (-1e30f)

// logits MFMA tiling
#define RT2_  18           // ceil(R/128)
#define PR2_  2304         // RT2*128
#define S_    24           // K-splits (each 2048)
#define NTIL_ 7            // 112 padded cols / 16
#define KT_   1536         // HB/32 k-steps total

typedef _Float16 h2   __attribute__((ext_vector_type(2)));
typedef _Float16 f16x8 __attribute__((ext_vector_type(8)));
typedef float    f32x4 __attribute__((ext_vector_type(4)));

__device__ inline uint pkh(float lo, float hi) {      // fast RTZ pack
    union { __fp16 v __attribute__((ext_vector_type(2))); uint u; } c;
    c.v = __builtin_amdgcn_cvt_pkrtz(lo, hi);
    return c.u;
}
__device__ inline ushort h_rne(float x) {
    union { _Float16 h; ushort u; } c; c.h = (_Float16)x; return c.u;
}
__device__ inline uint h2_rne(float lo, float hi) {
    return (uint)h_rne(lo) | ((uint)h_rne(hi) << 16);
}

// ---------------- fused pack + ent_att + ent_emb ---------------------------
// block ranges: [0,1152) ent_att | [1152,3840) Wb | [3840,4416) Wh |
//               [4416,4992) Wt | [4992,6528) seq | [6528,6624) ent_emb
#define PKB_ATT 1152
#define PKB_WB  2688
#define PKB_W   576      // 48kt*48nt*64lane = 147456 = 576*256 EXACT
#define PKB_SEQ 1536
#define PKB_EMB 96
__global__ void k_pack(const float* __restrict__ att, const float* __restrict__ Wb,
                       const float* __restrict__ Wh, const float* __restrict__ Wt,
                       const float* __restrict__ seq,
                       const int* __restrict__ midx, const float* __restrict__ mmask,
                       _Float16* __restrict__ ea, _Float16* __restrict__ WbP,
                       _Float16* __restrict__ WhP, _Float16* __restrict__ WtP,
                       _Float16* __restrict__ seqP, _Float16* __restrict__ ee) {
    int bid = blockIdx.x;
    if (bid < PKB_ATT) {                    // entity_atts -> fp16
        int blk = bid;                      // (b*E+e)*NH + n
        int n  = blk % NH_;
        int be = blk / NH_;
        int b  = be / E_;
        int idx[M_]; float msk[M_]; float denom = 0.f;
#pragma unroll
        for (int m = 0; m < M_; ++m) { idx[m] = midx[be*M_+m]; msk[m] = mmask[be*M_+m]; denom += msk[m]; }
        float inv = 1.f / denom;
        const float* abase = att + (size_t)(b*NH_ + n) * L_ * L_;
        for (int lp = threadIdx.x; lp < 512; lp += 256) {
            float s0 = 0.f, s1 = 0.f;
#pragma unroll
            for (int m = 0; m < M_; ++m) {
                float2 a = *(const float2*)(abase + idx[m]*L_ + 2*lp);
                s0 += msk[m]*a.x; s1 += msk[m]*a.y;
            }
            *(uint*)(ea + (((size_t)(be*NH_ + n)) << 10) + 2*lp) = pkh(s0*inv, s1*inv);
        }
        return;
    }
    if (bid < PKB_ATT + PKB_WB) {           // Wb -> [kt][nt][lane][8]
        int t = (bid - PKB_ATT)*256 + threadIdx.x;
        int lane = t & 63;
        int nt   = (t >> 6) % NTIL_;
        int kt   = t / (NTIL_*64);
        int n = nt*16 + (lane & 15);
        int k = kt*32 + ((lane >> 4) << 3);
        uint w[4] = {0u,0u,0u,0u};
        if (n < NL_) {
            const float* src = Wb + (size_t)n*HB_ + k;
#pragma unroll
            for (int e = 0; e < 4; ++e) w[e] = h2_rne(src[2*e], src[2*e+1]);
        }
        *(uint4*)(WbP + (size_t)t*8) = make_uint4(w[0],w[1],w[2],w[3]);
        return;
    }
    if (bid < PKB_ATT + PKB_WB + 2*PKB_W) { // Wh / Wt -> [kt][nt][lane][8]
        int seg = bid - PKB_ATT - PKB_WB;
        const float* W = (seg < PKB_W) ? Wh : Wt;
        _Float16*   WP = (seg < PKB_W) ? WhP : WtP;
        int t = (seg % PKB_W)*256 + threadIdx.x;
        int lane = t & 63;
        int nt   = (t >> 6) % 48;
        int kt   = t / (48*64);
        int n = nt*16 + (lane & 15);
        int k = kt*32 + ((lane >> 4) << 3);
        const float* src = W + (size_t)n*H2_ + k;
        uint w[4];
#pragma unroll
        for (int e = 0; e < 4; ++e) w[e] = h2_rne(src[2*e], src[2*e+1]);
        *(uint4*)(WP + (size_t)t*8) = make_uint4(w[0],w[1],w[2],w[3]);
        return;
    }
    if (bid < PKB_ATT + PKB_WB + 2*PKB_W + PKB_SEQ) {   // seq -> per-b frag
        int t = (bid - PKB_ATT - PKB_WB - 2*PKB_W)*256 + threadIdx.x;
        int lane = t & 63;
        int rest = t >> 6;
        int nt = rest % 48; rest /= 48;
        int kt = rest % 32;
        int b  = rest / 32;
        int n = nt*16 + (lane & 15);
        int k = kt*32 + ((lane >> 4) << 3);
        const float* src = seq + ((size_t)(b*L_ + k))*H_ + n;
        uint w[4];
#pragma unroll
        for (int e = 0; e < 4; ++e) w[e] = h2_rne(src[(2*e)*H_], src[(2*e+1)*H_]);
        *(uint4*)(seqP + (size_t)t*8) = make_uint4(w[0],w[1],w[2],w[3]);
        return;
    }
    // ent_emb: logsumexp over mentions -> fp16
    int be = bid - (PKB_ATT + PKB_WB + 2*PKB_W + PKB_SEQ);
    int b  = be / E_;
    int idx[M_]; float msk[M_];
#pragma unroll
    for (int m = 0; m < M_; ++m) { idx[m] = midx[be*M_+m]; msk[m] = mmask[be*M_+m]; }
    for (int d = threadIdx.x; d < H_; d += 256) {
        float v[M_]; float mx = NEG_;
#pragma unroll
        for (int m = 0; m < M_; ++m) {
            v[m] = (msk[m] > 0.f) ? seq[(b*L_ + idx[m])*H_ + d] : NEG_;
            mx = fmaxf(mx, v[m]);
        }
        float s = 0.f;
#pragma unroll
        for (int m = 0; m < M_; ++m) s += expf(v[m] - mx);
        ee[be*H_ + d] = (_Float16)(mx + logf(s));
    }
}

// ---------------- K3: ht_att (fp16 in/out, regs only) ----------------------
__global__ void k_ht_att(const _Float16* __restrict__ ea, const int* __restrict__ hts,
                         _Float16* __restrict__ ht) {
    __shared__ float red[4];
    int bp = blockIdx.x;            // b*P+p
    int b  = bp / P_;
    int h = hts[bp*2+0], t = hts[bp*2+1];
    const h2* eh2 = (const h2*)(ea + ((size_t)(b*E_ + h)*NH_ << 10));
    const h2* et2 = (const h2*)(ea + ((size_t)(b*E_ + t)*NH_ << 10));
    int lp = threadIdx.x;           // each thread: 4 consecutive l = lp*4..+3
    float s0 = 0.f, s1 = 0.f, s2 = 0.f, s3 = 0.f;
#pragma unroll
    for (int n = 0; n < NH_; ++n) {
        const h2* ph = eh2 + n*512 + lp*2;
        const h2* pt = et2 + n*512 + lp*2;
        h2 a0 = ph[0], a1 = ph[1];
        h2 c0 = pt[0], c1 = pt[1];
        s0 += (float)a0[0]*(float)c0[0];
        s1 += (float)a0[1]*(float)c0[1];
        s2 += (float)a1[0]*(float)c1[0];
        s3 += (float)a1[1]*(float)c1[1];
    }
    s0 *= (1.f/NH_); s1 *= (1.f/NH_); s2 *= (1.f/NH_); s3 *= (1.f/NH_);
    float local = s0 + s1 + s2 + s3;
#pragma unroll
    for (int o = 32; o > 0; o >>= 1) local += __shfl_down(local, o);
    int wid = threadIdx.x >> 6, lane = threadIdx.x & 63;
    if (lane == 0) red[wid] = local;
    __syncthreads();
    if (threadIdx.x == 0) red[0] = 1.f / (red[0]+red[1]+red[2]+red[3] + 1e-5f);
    __syncthreads();
    float inv = red[0];
    *(uint2*)(ht + ((size_t)bp << 10) + lp*4) =
        make_uint2(pkh(s0*inv, s1*inv), pkh(s2*inv, s3*inv));
}

// ---------------- K4: rs = ht @ seq via fp16 MFMA (reg-dbuf staging) -------
// grid (9, 12, B): BM=64 p-rows, BN=64 d-cols, K=1024 in 16 chunks of 64
__launch_bounds__(256, 4)
__global__ void k_rs_mfma(const _Float16* __restrict__ ht, const _Float16* __restrict__ seqP,
                          _Float16* __restrict__ rs) {
    __shared__ _Float16 as[64*72];
    int p0  = blockIdx.x * 64;
    int nt0 = blockIdx.y * 4;
    int b   = blockIdx.z;
    int wave = threadIdx.x >> 6, lane = threadIdx.x & 63;

    // per-thread staging addresses (2 stores of uint4 per phase)
    const _Float16* srcp[2];
    int ldst[2];
#pragma unroll
    for (int i = 0; i < 2; ++i) {
        int t = threadIdx.x + i*256;
        int row = t >> 3, c8 = (t & 7)*8;
        int p = p0 + row;
        srcp[i] = (p < P_) ? ht + (((size_t)(b*P_ + p)) << 10) + c8 : nullptr;
        ldst[i] = row*72 + c8;
    }
    uint4 st[2];
#pragma unroll
    for (int i = 0; i < 2; ++i)
        st[i] = srcp[i] ? *(const uint4*)(srcp[i]) : make_uint4(0,0,0,0);

    f32x4 acc[4] = {};
    const _Float16* wbase = seqP + ((size_t)b*32*48 + nt0)*512 + lane*8;
    int rowA = wave*16 + (lane & 15);
    int asub = (lane >> 4) << 3;

    for (int kc = 0; kc < 16; ++kc) {
        if (kc) __syncthreads();
#pragma unroll
        for (int i = 0; i < 2; ++i) *(uint4*)(as + ldst[i]) = st[i];
        __syncthreads();
        if (kc + 1 < 16) {
#pragma unroll
            for (int i = 0; i < 2; ++i)
                st[i] = srcp[i] ? *(const uint4*)(srcp[i] + (kc+1)*64) : make_uint4(0,0,0,0);
        }
#pragma unroll
        for (int kk = 0; kk < 2; ++kk) {
            int kt = kc*2 + kk;
            const _Float16* wp = wbase + (size_t)kt*(48*512);
            f16x8 bf[4];
#pragma unroll
            for (int j = 0; j < 4; ++j) bf[j] = *(const f16x8*)(wp + j*512);
            f16x8 af = *(const f16x8*)(as + rowA*72 + kk*32 + asub);
#pragma unroll
            for (int j = 0; j < 4; ++j)
                acc[j] = __builtin_amdgcn_mfma_f32_16x16x32_f16(af, bf[j], acc[j], 0, 0, 0);
        }
    }
    int crow = (lane >> 4) * 4;
    int ccol = lane & 15;
#pragma unroll
    for (int j = 0; j < 4; ++j) {
        int n = nt0*16 + j*16 + ccol;
#pragma unroll
        for (int reg = 0; reg < 4; ++reg) {
            int p = p0 + wave*16 + crow + reg;
            if (p < P_) rs[(size_t)(b*P_ + p)*H_ + n] = (_Float16)acc[j][reg];
        }
    }
}

// ---------------- K5: zh & zt via fp16 MFMA (one launch, reg-dbuf) ---------
// grid (35, 12, 2): BM=64, BN=64, K=1536 in 24 chunks of 64
__launch_bounds__(256, 4)
__global__ void k_z_mfma(const _Float16* __restrict__ ee, const _Float16* __restrict__ rs,
                         const _Float16* __restrict__ WhP, const _Float16* __restrict__ WtP,
                         const float* __restrict__ bh, const float* __restrict__ bt,
                         const int* __restrict__ hts,
                         _Float16* __restrict__ zh, _Float16* __restrict__ zt) {
    __shared__ _Float16 as[64*72];
    int which = blockIdx.z;
    const _Float16* WP   = which ? WtP : WhP;
    const float*    bias = which ? bt  : bh;
    _Float16*       out  = which ? zt  : zh;
    int r0  = blockIdx.x * 64;
    int nt0 = blockIdx.y * 4;
    int wave = threadIdx.x >> 6, lane = threadIdx.x & 63;

    // per-thread staging addresses: srcA (gathered ee) for kc<12, srcB (rs) after
    const _Float16* srcA[2];
    const _Float16* srcB[2];
    int ldst[2];
#pragma unroll
    for (int i = 0; i < 2; ++i) {
        int t = threadIdx.x + i*256;
        int row = t >> 3, c8 = (t & 7)*8;
        int r = r0 + row;
        if (r < R_) {
            int b = r / P_;
            int eidx = hts[r*2 + which];
            srcA[i] = ee + (size_t)(b*E_ + eidx)*H_ + c8;
            srcB[i] = rs + (size_t)r*H_ + c8;
        } else { srcA[i] = nullptr; srcB[i] = nullptr; }
        ldst[i] = row*72 + c8;
    }
    uint4 st[2];
#pragma unroll
    for (int i = 0; i < 2; ++i)
        st[i] = srcA[i] ? *(const uint4*)(srcA[i]) : make_uint4(0,0,0,0);

    f32x4 acc[4] = {};
    const _Float16* wbase = WP + (size_t)nt0*512 + lane*8;
    int rowA = wave*16 + (lane & 15);
    int asub = (lane >> 4) << 3;

    for (int kc = 0; kc < 24; ++kc) {
        if (kc) __syncthreads();
#pragma unroll
        for (int i = 0; i < 2; ++i) *(uint4*)(as + ldst[i]) = st[i];
        __syncthreads();
        if (kc + 1 < 24) {
            int kn = kc + 1;
#pragma unroll
            for (int i = 0; i < 2; ++i) {
                const _Float16* s = (kn < 12) ? (srcA[i] ? srcA[i] + kn*64 : nullptr)
                                              : (srcB[i] ? srcB[i] + (kn-12)*64 : nullptr);
                st[i] = s ? *(const uint4*)s : make_uint4(0,0,0,0);
            }
        }
#pragma unroll
        for (int kk = 0; kk < 2; ++kk) {
            int kt = kc*2 + kk;
            const _Float16* wp = wbase + (size_t)kt*(48*512);
            f16x8 bf[4];
#pragma unroll
            for (int j = 0; j < 4; ++j) bf[j] = *(const f16x8*)(wp + j*512);
            f16x8 af = *(const f16x8*)(as + rowA*72 + kk*32 + asub);
#pragma unroll
            for (int j = 0; j < 4; ++j)
                acc[j] = __builtin_amdgcn_mfma_f32_16x16x32_f16(af, bf[j], acc[j], 0, 0, 0);
        }
    }
    int crow = (lane >> 4) * 4;
    int ccol = lane & 15;
#pragma unroll
    for (int j = 0; j < 4; ++j) {
        int n = nt0*16 + j*16 + ccol;
        float bv = bias[n];
#pragma unroll
        for (int reg = 0; reg < 4; ++reg) {
            int r = r0 + wave*16 + crow + reg;
            if (r < R_) out[(size_t)r*H_ + n] = (_Float16)tanhf(acc[j][reg] + bv);
        }
    }
}

// ---------------- K6: logits partials via fp16 MFMA ------------------------
// grid 432 = RT2_*S_; BM=128, N=112, K-chunk 2048
__launch_bounds__(256, 2)
__global__ void k_logits_mfma(const _Float16* __restrict__ zh, const _Float16* __restrict__ zt,
                              const _Float16* __restrict__ WbP, float* __restrict__ part) {
    __shared__ _Float16 zhs[128*40];   // stride 40 halves (80B)
    __shared__ _Float16 zts[128*72];   // stride 72 halves (144B)
    int bid = blockIdx.x;
    int rt = bid % RT2_, kc = bid / RT2_;
    int r0 = rt * 128;
    int kblk = kc >> 1, i0 = (kc & 1) * 32;

    for (int t = threadIdx.x; t < 128*4; t += 256) {
        int row = t >> 2, i8 = (t & 3)*8;
        int r = r0 + row;
        uint4 w = make_uint4(0,0,0,0);
        if (r < R_) w = *(const uint4*)(zh + (size_t)r*H_ + kblk*64 + i0 + i8);
        *(uint4*)(zhs + row*40 + i8) = w;
    }
    for (int t = threadIdx.x; t < 128*8; t += 256) {
        int row = t >> 3, j8 = (t & 7)*8;
        int r = r0 + row;
        uint4 w = make_uint4(0,0,0,0);
        if (r < R_) w = *(const uint4*)(zt + (size_t)r*H_ + kblk*64 + j8);
        *(uint4*)(zts + row*72 + j8) = w;
    }
    __syncthreads();

    int wave = threadIdx.x >> 6, lane = threadIdx.x & 63;
    int rowA0 = wave*32 + (lane & 15);
    int jsub  = (lane >> 4) * 8;

    f32x4 acc[2][NTIL_] = {};
    const _Float16* wb0 = WbP + (size_t)(kc*64) * (NTIL_*512) + lane*8;

#pragma unroll 2
    for (int ktl = 0; ktl < 64; ++ktl) {
        const _Float16* wp = wb0 + (size_t)ktl * (NTIL_*512);
        f16x8 bf[NTIL_];
#pragma unroll
        for (int nt = 0; nt < NTIL_; ++nt)
            bf[nt] = *(const f16x8*)(wp + nt*512);
        int il = ktl >> 1;
        int jb = (ktl & 1) * 32 + jsub;
#pragma unroll
        for (int ms = 0; ms < 2; ++ms) {
            int row = rowA0 + ms*16;
            _Float16 hv = zhs[row*40 + il];
            h2 hb = {hv, hv};
            union { uint4 u; h2 v[4]; } T;
            T.u = *(const uint4*)(zts + row*72 + jb);
            union { h2 v[4]; f16x8 f; } A;
            A.v[0] = hb * T.v[0];
            A.v[1] = hb * T.v[1];
            A.v[2] = hb * T.v[2];
            A.v[3] = hb * T.v[3];
#pragma unroll
            for (int nt = 0; nt < NTIL_; ++nt)
                acc[ms][nt] = __builtin_amdgcn_mfma_f32_16x16x32_f16(A.f, bf[nt], acc[ms][nt], 0, 0, 0);
        }
    }

    int crow0 = wave*32 + (lane >> 4) * 4;
    int ccol  = lane & 15;
#pragma unroll
    for (int ms = 0; ms < 2; ++ms) {
#pragma unroll
        for (int nt = 0; nt < NTIL_; ++nt) {
#pragma unroll
            for (int reg = 0; reg < 4; ++reg) {
                int rp = r0 + crow0 + ms*16 + reg;
                part[((size_t)kc*PR2_ + rp)*112 + nt*16 + ccol] = acc[ms][nt][reg];
            }
        }
    }
}

// ---------------- K7: reduce partials + bias ------------------------------
__global__ void k_logits_reduce(const float* __restrict__ part, const float* __restrict__ bb,
                                float* __restrict__ out) {
    int idx = blockIdx.x*256 + threadIdx.x;
    if (idx >= R_*NL_) return;
    int r = idx / NL_, n = idx - r*NL_;
    float s = bb[n];
#pragma unroll
    for (int kc = 0; kc < S_; ++kc) s += part[((size_t)kc*PR2_ + r)*112 + n];
    out[idx] = s;
}

extern "C" void kernel_launch(void* const* d_in, const int* in_sizes, int n_in,
                              void* d_out, int out_size, void* d_ws, size_t ws_size,
                              hipStream_t stream) {
    const float* seq   = (const float*)d_in[0];
    const float* att   = (const float*)d_in[1];
    const float* mmask = (const float*)d_in[2];
    const float* Wh    = (const float*)d_in[3];
    const float* bh    = (const float*)d_in[4];
    const float* Wt    = (const float*)d_in[5];
    const float* bt    = (const float*)d_in[6];
    const float* Wb    = (const float*)d_in[7];
    const float* bb    = (const float*)d_in[8];
    const int*   midx  = (const int*)d_in[9];
    const int*   hts   = (const int*)d_in[10];
    float* out = (float*)d_out;

    // workspace carve (no aliasing; ws is large, we use ~60MB)
    char* base = (char*)d_ws;
    _Float16* WbP  = (_Float16*)base;  base += (size_t)KT_*NTIL_*64*8 * 2;      // 11.0 MB
    _Float16* WhP  = (_Float16*)base;  base += (size_t)48*48*64*8 * 2;          //  2.4 MB
    _Float16* WtP  = (_Float16*)base;  base += (size_t)48*48*64*8 * 2;          //  2.4 MB
    _Float16* seqP = (_Float16*)base;  base += (size_t)B_*32*48*64*8 * 2;       //  6.3 MB
    _Float16* ee   = (_Float16*)base;  base += (size_t)B_*E_*H_ * 2;            //  0.15 MB
    _Float16* ea   = (_Float16*)base;  base += (size_t)B_*E_*NH_*L_ * 2;        //  2.4 MB
    _Float16* ht   = (_Float16*)base;  base += (size_t)R_*L_ * 2;               //  4.5 MB
    _Float16* rs   = (_Float16*)base;  base += (size_t)R_*H_ * 2;               //  3.4 MB
    _Float16* zh   = (_Float16*)base;  base += (size_t)R_*H_ * 2;               //  3.4 MB
    _Float16* zt   = (_Float16*)base;  base += (size_t)R_*H_ * 2;               //  3.4 MB
    float*    part = (float*)base;                                              // 24.8 MB

    k_pack<<<dim3(PKB_ATT + PKB_WB + 2*PKB_W + PKB_SEQ + PKB_EMB), dim3(256), 0, stream>>>(
        att, Wb, Wh, Wt, seq, midx, mmask, ea, WbP, WhP, WtP, seqP, ee);

    k_ht_att<<<dim3(R_), dim3(256), 0, stream>>>(ea, hts, ht);

    k_rs_mfma<<<dim3(9, 12, B_), dim3(256), 0, stream>>>(ht, seqP, rs);

    k_z_mfma<<<dim3(35, 12, 2), dim3(256), 0, stream>>>(ee, rs, WhP, WtP, bh, bt, hts, zh, zt);

    k_logits_mfma  <<<dim3(RT2_*S_), dim3(256), 0, stream>>>(zh, zt, WbP, part);
    k_logits_reduce<<<dim3((R_*NL_ + 255)/256), dim3(256), 0, stream>>>(part, bb, out);
}

// Round 8
// 122.844 us; speedup vs baseline: 9.4501x; 1.2393x over previous
//
#include <hip/hip_runtime.h>
#include <math.h>

#define B_   4
#define L_   1024
#define H_   768
#define NH_  12
#define E_   24
#define M_   4
#define P_   552
#define NL_  97
#define H2_  1536          // 2*H
#define HB_  49152         // H*BLK
#define R_   2208          // B*P
#define NEG_ (-1e30f)

// logits MFMA tiling: BM=256, 9 r-tiles, 24 K-chunks of 2048
#define RT2_  9
#define PR2_  2304         // RT2*256
#define S_    24
#define NTIL_ 7            // 112 padded cols / 16
#define KT_   1536         // HB/32 k-steps total

typedef _Float16 h2   __attribute__((ext_vector_type(2)));
typedef _Float16 f16x8 __attribute__((ext_vector_type(8)));
typedef float    f32x4 __attribute__((ext_vector_type(4)));

__device__ inline uint pkh(float lo, float hi) {      // fast RTZ pack
    union { __fp16 v __attribute__((ext_vector_type(2))); uint u; } c;
    c.v = __builtin_amdgcn_cvt_pkrtz(lo, hi);
    return c.u;
}
__device__ inline ushort h_rne(float x) {
    union { _Float16 h; ushort u; } c; c.h = (_Float16)x; return c.u;
}
__device__ inline uint h2_rne(float lo, float hi) {
    return (uint)h_rne(lo) | ((uint)h_rne(hi) << 16);
}

// ---------------- fused pack + ent_att + ent_emb ---------------------------
#define PKB_ATT 1152
#define PKB_WB  2688
#define PKB_W   576      // 48kt*48nt*64lane = 147456 = 576*256 EXACT
#define PKB_SEQ 1536
#define PKB_EMB 96
__global__ void k_pack(const float* __restrict__ att, const float* __restrict__ Wb,
                       const float* __restrict__ Wh, const float* __restrict__ Wt,
                       const float* __restrict__ seq,
                       const int* __restrict__ midx, const float* __restrict__ mmask,
                       _Float16* __restrict__ ea, _Float16* __restrict__ WbP,
                       _Float16* __restrict__ WhP, _Float16* __restrict__ WtP,
                       _Float16* __restrict__ seqP, _Float16* __restrict__ ee) {
    int bid = blockIdx.x;
    if (bid < PKB_ATT) {                    // entity_atts -> fp16 (float4 loads)
        int blk = bid;                      // (b*E+e)*NH + n
        int n  = blk % NH_;
        int be = blk / NH_;
        int b  = be / E_;
        int idx[M_]; float msk[M_]; float denom = 0.f;
#pragma unroll
        for (int m = 0; m < M_; ++m) { idx[m] = midx[be*M_+m]; msk[m] = mmask[be*M_+m]; denom += msk[m]; }
        float inv = 1.f / denom;
        const float* abase = att + (size_t)(b*NH_ + n) * L_ * L_;
        int l4 = threadIdx.x * 4;           // 256 threads x 4 = 1024
        float s0 = 0.f, s1 = 0.f, s2 = 0.f, s3 = 0.f;
#pragma unroll
        for (int m = 0; m < M_; ++m) {
            float4 a = *(const float4*)(abase + idx[m]*L_ + l4);
            s0 += msk[m]*a.x; s1 += msk[m]*a.y; s2 += msk[m]*a.z; s3 += msk[m]*a.w;
        }
        *(uint2*)(ea + (((size_t)(be*NH_ + n)) << 10) + l4) =
            make_uint2(pkh(s0*inv, s1*inv), pkh(s2*inv, s3*inv));
        return;
    }
    if (bid < PKB_ATT + PKB_WB) {           // Wb -> [kt][nt][lane][8]
        int t = (bid - PKB_ATT)*256 + threadIdx.x;
        int lane = t & 63;
        int nt   = (t >> 6) % NTIL_;
        int kt   = t / (NTIL_*64);
        int n = nt*16 + (lane & 15);
        int k = kt*32 + ((lane >> 4) << 3);
        uint w[4] = {0u,0u,0u,0u};
        if (n < NL_) {
            const float* src = Wb + (size_t)n*HB_ + k;
#pragma unroll
            for (int e = 0; e < 4; ++e) w[e] = h2_rne(src[2*e], src[2*e+1]);
        }
        *(uint4*)(WbP + (size_t)t*8) = make_uint4(w[0],w[1],w[2],w[3]);
        return;
    }
    if (bid < PKB_ATT + PKB_WB + 2*PKB_W) { // Wh / Wt -> [kt][nt][lane][8]
        int seg = bid - PKB_ATT - PKB_WB;
        const float* W = (seg < PKB_W) ? Wh : Wt;
        _Float16*   WP = (seg < PKB_W) ? WhP : WtP;
        int t = (seg % PKB_W)*256 + threadIdx.x;
        int lane = t & 63;
        int nt   = (t >> 6) % 48;
        int kt   = t / (48*64);
        int n = nt*16 + (lane & 15);
        int k = kt*32 + ((lane >> 4) << 3);
        const float* src = W + (size_t)n*H2_ + k;
        uint w[4];
#pragma unroll
        for (int e = 0; e < 4; ++e) w[e] = h2_rne(src[2*e], src[2*e+1]);
        *(uint4*)(WP + (size_t)t*8) = make_uint4(w[0],w[1],w[2],w[3]);
        return;
    }
    if (bid < PKB_ATT + PKB_WB + 2*PKB_W + PKB_SEQ) {   // seq -> per-b frag
        int t = (bid - PKB_ATT - PKB_WB - 2*PKB_W)*256 + threadIdx.x;
        int lane = t & 63;
        int rest = t >> 6;
        int nt = rest % 48; rest /= 48;
        int kt = rest % 32;
        int b  = rest / 32;
        int n = nt*16 + (lane & 15);
        int k = kt*32 + ((lane >> 4) << 3);
        const float* src = seq + ((size_t)(b*L_ + k))*H_ + n;
        uint w[4];
#pragma unroll
        for (int e = 0; e < 4; ++e) w[e] = h2_rne(src[(2*e)*H_], src[(2*e+1)*H_]);
        *(uint4*)(seqP + (size_t)t*8) = make_uint4(w[0],w[1],w[2],w[3]);
        return;
    }
    // ent_emb: logsumexp over mentions -> fp16
    int be = bid - (PKB_ATT + PKB_WB + 2*PKB_W + PKB_SEQ);
    int b  = be / E_;
    int idx[M_]; float msk[M_];
#pragma unroll
    for (int m = 0; m < M_; ++m) { idx[m] = midx[be*M_+m]; msk[m] = mmask[be*M_+m]; }
    for (int d = threadIdx.x; d < H_; d += 256) {
        float v[M_]; float mx = NEG_;
#pragma unroll
        for (int m = 0; m < M_; ++m) {
            v[m] = (msk[m] > 0.f) ? seq[(b*L_ + idx[m])*H_ + d] : NEG_;
            mx = fmaxf(mx, v[m]);
        }
        float s = 0.f;
#pragma unroll
        for (int m = 0; m < M_; ++m) s += expf(v[m] - mx);
        ee[be*H_ + d] = (_Float16)(mx + logf(s));
    }
}

// ---------------- K3: ht_att (128 threads, 16B loads) ----------------------
__global__ void k_ht_att(const _Float16* __restrict__ ea, const int* __restrict__ hts,
                         _Float16* __restrict__ ht) {
    __shared__ float red[2];
    int bp = blockIdx.x;            // b*P+p
    int b  = bp / P_;
    int h = hts[bp*2+0], t = hts[bp*2+1];
    const uint4* eh4 = (const uint4*)(ea + ((size_t)(b*E_ + h)*NH_ << 10));
    const uint4* et4 = (const uint4*)(ea + ((size_t)(b*E_ + t)*NH_ << 10));
    int lp = threadIdx.x;           // 0..127, each covers l = lp*8..+7
    float s[8] = {};
#pragma unroll
    for (int n = 0; n < NH_; ++n) {
        union { uint4 u; h2 v[4]; } A, C;
        A.u = eh4[n*128 + lp];
        C.u = et4[n*128 + lp];
#pragma unroll
        for (int q = 0; q < 4; ++q) {
            s[2*q]   += (float)A.v[q][0]*(float)C.v[q][0];
            s[2*q+1] += (float)A.v[q][1]*(float)C.v[q][1];
        }
    }
    float local = 0.f;
#pragma unroll
    for (int q = 0; q < 8; ++q) { s[q] *= (1.f/NH_); local += s[q]; }
#pragma unroll
    for (int o = 32; o > 0; o >>= 1) local += __shfl_down(local, o);
    int wid = threadIdx.x >> 6, lane = threadIdx.x & 63;
    if (lane == 0) red[wid] = local;
    __syncthreads();
    if (threadIdx.x == 0) red[0] = 1.f / (red[0] + red[1] + 1e-5f);
    __syncthreads();
    float inv = red[0];
    *(uint4*)(ht + ((size_t)bp << 10) + lp*8) =
        make_uint4(pkh(s[0]*inv, s[1]*inv), pkh(s[2]*inv, s[3]*inv),
                   pkh(s[4]*inv, s[5]*inv), pkh(s[6]*inv, s[7]*inv));
}

// ---------------- K4: rs = ht @ seq via fp16 MFMA (XCD-swizzled) -----------
// flat grid 432: xcd=bid&7 -> b=xcd>>1 (seqP L2-resident per XCD)
__launch_bounds__(256, 4)
__global__ void k_rs_mfma(const _Float16* __restrict__ ht, const _Float16* __restrict__ seqP,
                          _Float16* __restrict__ rs) {
    __shared__ _Float16 as[64*72];
    int bid = blockIdx.x;
    int xcd = bid & 7, j = bid >> 3;     // j 0..53
    int b    = xcd >> 1;
    int tile = (xcd & 1)*54 + j;         // 0..107
    int p0   = (tile % 9) * 64;
    int nt0  = (tile / 9) * 4;
    int wave = threadIdx.x >> 6, lane = threadIdx.x & 63;

    const _Float16* srcp[2];
    int ldst[2];
#pragma unroll
    for (int i = 0; i < 2; ++i) {
        int t = threadIdx.x + i*256;
        int row = t >> 3, c8 = (t & 7)*8;
        int p = p0 + row;
        srcp[i] = (p < P_) ? ht + (((size_t)(b*P_ + p)) << 10) + c8 : nullptr;
        ldst[i] = row*72 + c8;
    }
    uint4 st[2];
#pragma unroll
    for (int i = 0; i < 2; ++i)
        st[i] = srcp[i] ? *(const uint4*)(srcp[i]) : make_uint4(0,0,0,0);

    f32x4 acc[4] = {};
    const _Float16* wbase = seqP + ((size_t)b*32*48 + nt0)*512 + lane*8;
    int rowA = wave*16 + (lane & 15);
    int asub = (lane >> 4) << 3;

    for (int kc = 0; kc < 16; ++kc) {
        if (kc) __syncthreads();
#pragma unroll
        for (int i = 0; i < 2; ++i) *(uint4*)(as + ldst[i]) = st[i];
        __syncthreads();
        if (kc + 1 < 16) {
#pragma unroll
            for (int i = 0; i < 2; ++i)
                st[i] = srcp[i] ? *(const uint4*)(srcp[i] + (kc+1)*64) : make_uint4(0,0,0,0);
        }
#pragma unroll
        for (int kk = 0; kk < 2; ++kk) {
            int kt = kc*2 + kk;
            const _Float16* wp = wbase + (size_t)kt*(48*512);
            f16x8 bf[4];
#pragma unroll
            for (int jj = 0; jj < 4; ++jj) bf[jj] = *(const f16x8*)(wp + jj*512);
            f16x8 af = *(const f16x8*)(as + rowA*72 + kk*32 + asub);
#pragma unroll
            for (int jj = 0; jj < 4; ++jj)
                acc[jj] = __builtin_amdgcn_mfma_f32_16x16x32_f16(af, bf[jj], acc[jj], 0, 0, 0);
        }
    }
    int crow = (lane >> 4) * 4;
    int ccol = lane & 15;
#pragma unroll
    for (int jj = 0; jj < 4; ++jj) {
        int n = nt0*16 + jj*16 + ccol;
#pragma unroll
        for (int reg = 0; reg < 4; ++reg) {
            int p = p0 + wave*16 + crow + reg;
            if (p < P_) rs[(size_t)(b*P_ + p)*H_ + n] = (_Float16)acc[jj][reg];
        }
    }
}

// ---------------- K5: zh & zt via fp16 MFMA (XCD-swizzled which) -----------
// flat grid 840: xcd=bid&7 -> which=xcd>>2 (WhP or WtP L2-resident per XCD)
__launch_bounds__(256, 4)
__global__ void k_z_mfma(const _Float16* __restrict__ ee, const _Float16* __restrict__ rs,
                         const _Float16* __restrict__ WhP, const _Float16* __restrict__ WtP,
                         const float* __restrict__ bh, const float* __restrict__ bt,
                         const int* __restrict__ hts,
                         _Float16* __restrict__ zh, _Float16* __restrict__ zt) {
    __shared__ _Float16 as[64*72];
    int bid = blockIdx.x;
    int xcd = bid & 7, j = bid >> 3;     // j 0..104
    int which = xcd >> 2;
    int tile  = (xcd & 3)*105 + j;       // 0..419
    int r0  = (tile % 35) * 64;
    int nt0 = (tile / 35) * 4;
    const _Float16* WP   = which ? WtP : WhP;
    const float*    bias = which ? bt  : bh;
    _Float16*       out  = which ? zt  : zh;
    int wave = threadIdx.x >> 6, lane = threadIdx.x & 63;

    const _Float16* srcA[2];
    const _Float16* srcB[2];
    int ldst[2];
#pragma unroll
    for (int i = 0; i < 2; ++i) {
        int t = threadIdx.x + i*256;
        int row = t >> 3, c8 = (t & 7)*8;
        int r = r0 + row;
        if (r < R_) {
            int b = r / P_;
            int eidx = hts[r*2 + which];
            srcA[i] = ee + (size_t)(b*E_ + eidx)*H_ + c8;
            srcB[i] = rs + (size_t)r*H_ + c8;
        } else { srcA[i] = nullptr; srcB[i] = nullptr; }
        ldst[i] = row*72 + c8;
    }
    uint4 st[2];
#pragma unroll
    for (int i = 0; i < 2; ++i)
        st[i] = srcA[i] ? *(const uint4*)(srcA[i]) : make_uint4(0,0,0,0);

    f32x4 acc[4] = {};
    const _Float16* wbase = WP + (size_t)nt0*512 + lane*8;
    int rowA = wave*16 + (lane & 15);
    int asub = (lane >> 4) << 3;

    for (int kc = 0; kc < 24; ++kc) {
        if (kc) __syncthreads();
#pragma unroll
        for (int i = 0; i < 2; ++i) *(uint4*)(as + ldst[i]) = st[i];
        __syncthreads();
        if (kc + 1 < 24) {
            int kn = kc + 1;
#pragma unroll
            for (int i = 0; i < 2; ++i) {
                const _Float16* s = (kn < 12) ? (srcA[i] ? srcA[i] + kn*64 : nullptr)
                                              : (srcB[i] ? srcB[i] + (kn-12)*64 : nullptr);
                st[i] = s ? *(const uint4*)s : make_uint4(0,0,0,0);
            }
        }
#pragma unroll
        for (int kk = 0; kk < 2; ++kk) {
            int kt = kc*2 + kk;
            const _Float16* wp = wbase + (size_t)kt*(48*512);
            f16x8 bf[4];
#pragma unroll
            for (int jj = 0; jj < 4; ++jj) bf[jj] = *(const f16x8*)(wp + jj*512);
            f16x8 af = *(const f16x8*)(as + rowA*72 + kk*32 + asub);
#pragma unroll
            for (int jj = 0; jj < 4; ++jj)
                acc[jj] = __builtin_amdgcn_mfma_f32_16x16x32_f16(af, bf[jj], acc[jj], 0, 0, 0);
        }
    }
    int crow = (lane >> 4) * 4;
    int ccol = lane & 15;
#pragma unroll
    for (int jj = 0; jj < 4; ++jj) {
        int n = nt0*16 + jj*16 + ccol;
        float bv = bias[n];
#pragma unroll
        for (int reg = 0; reg < 4; ++reg) {
            int r = r0 + wave*16 + crow + reg;
            if (r < R_) out[(size_t)r*H_ + n] = (_Float16)tanhf(acc[jj][reg] + bv);
        }
    }
}

// ---------------- K6: logits v2 — BM=256, 8 waves, XCD-grouped kc ----------
// flat grid 216: xcd=bid&7 -> kc in {xcd*3..xcd*3+2} (1.4MB WbP per XCD L2)
__launch_bounds__(512, 2)
__global__ void k_logits_mfma(const _Float16* __restrict__ zh, const _Float16* __restrict__ zt,
                              const _Float16* __restrict__ WbP, float* __restrict__ part) {
    __shared__ _Float16 zhs[256*40];   // 20 KB
    __shared__ _Float16 zts[256*72];   // 36.9 KB
    int bid = blockIdx.x;
    int xcd = bid & 7, j = bid >> 3;   // j 0..26
    int kc  = xcd*3 + j/9;             // 0..23
    int rt  = j % 9;
    int r0  = rt * 256;
    int kblk = kc >> 1, i0 = (kc & 1) * 32;

    for (int t = threadIdx.x; t < 256*4; t += 512) {
        int row = t >> 2, i8 = (t & 3)*8;
        int r = r0 + row;
        uint4 w = make_uint4(0,0,0,0);
        if (r < R_) w = *(const uint4*)(zh + (size_t)r*H_ + kblk*64 + i0 + i8);
        *(uint4*)(zhs + row*40 + i8) = w;
    }
    for (int t = threadIdx.x; t < 256*8; t += 512) {
        int row = t >> 3, j8 = (t & 7)*8;
        int r = r0 + row;
        uint4 w = make_uint4(0,0,0,0);
        if (r < R_) w = *(const uint4*)(zt + (size_t)r*H_ + kblk*64 + j8);
        *(uint4*)(zts + row*72 + j8) = w;
    }
    __syncthreads();

    int wave = threadIdx.x >> 6, lane = threadIdx.x & 63;
    int rowA0 = wave*32 + (lane & 15);
    int jsub  = (lane >> 4) * 8;

    f32x4 acc[2][NTIL_] = {};
    const _Float16* wb0 = WbP + (size_t)(kc*64) * (NTIL_*512) + lane*8;

    f16x8 bf[NTIL_];
#pragma unroll
    for (int nt = 0; nt < NTIL_; ++nt) bf[nt] = *(const f16x8*)(wb0 + nt*512);

    for (int ktl = 0; ktl < 64; ++ktl) {
        f16x8 bn[NTIL_];
        if (ktl + 1 < 64) {
            const _Float16* wp = wb0 + (size_t)(ktl+1) * (NTIL_*512);
#pragma unroll
            for (int nt = 0; nt < NTIL_; ++nt) bn[nt] = *(const f16x8*)(wp + nt*512);
        }
        int il = ktl >> 1;
        int jb = (ktl & 1) * 32 + jsub;
#pragma unroll
        for (int ms = 0; ms < 2; ++ms) {
            int row = rowA0 + ms*16;
            _Float16 hv = zhs[row*40 + il];
            h2 hb = {hv, hv};
            union { uint4 u; h2 v[4]; } T;
            T.u = *(const uint4*)(zts + row*72 + jb);
            union { h2 v[4]; f16x8 f; } A;
            A.v[0] = hb * T.v[0];
            A.v[1] = hb * T.v[1];
            A.v[2] = hb * T.v[2];
            A.v[3] = hb * T.v[3];
#pragma unroll
            for (int nt = 0; nt < NTIL_; ++nt)
                acc[ms][nt] = __builtin_amdgcn_mfma_f32_16x16x32_f16(A.f, bf[nt], acc[ms][nt], 0, 0, 0);
        }
        if (ktl + 1 < 64) {
#pragma unroll
            for (int nt = 0; nt < NTIL_; ++nt) bf[nt] = bn[nt];
        }
    }

    int crow0 = wave*32 + (lane >> 4) * 4;
    int ccol  = lane & 15;
#pragma unroll
    for (int ms = 0; ms < 2; ++ms) {
#pragma unroll
        for (int nt = 0; nt < NTIL_; ++nt) {
#pragma unroll
            for (int reg = 0; reg < 4; ++reg) {
                int rp = r0 + crow0 + ms*16 + reg;
                part[((size_t)kc*PR2_ + rp)*112 + nt*16 + ccol] = acc[ms][nt][reg];
            }
        }
    }
}

// ---------------- K7: reduce partials + bias ------------------------------
__global__ void k_logits_reduce(const float* __restrict__ part, const float* __restrict__ bb,
                                float* __restrict__ out) {
    int idx = blockIdx.x*256 + threadIdx.x;
    if (idx >= R_*NL_) return;
    int r = idx / NL_, n = idx - r*NL_;
    float s = bb[n];
#pragma unroll
    for (int kc = 0; kc < S_; ++kc) s += part[((size_t)kc*PR2_ + r)*112 + n];
    out[idx] = s;
}

extern "C" void kernel_launch(void* const* d_in, const int* in_sizes, int n_in,
                              void* d_out, int out_size, void* d_ws, size_t ws_size,
                              hipStream_t stream) {
    const float* seq   = (const float*)d_in[0];
    const float* att   = (const float*)d_in[1];
    const float* mmask = (const float*)d_in[2];
    const float* Wh    = (const float*)d_in[3];
    const float* bh    = (const float*)d_in[4];
    const float* Wt    = (const float*)d_in[5];
    const float* bt    = (const float*)d_in[6];
    const float* Wb    = (const float*)d_in[7];
    const float* bb    = (const float*)d_in[8];
    const int*   midx  = (const int*)d_in[9];
    const int*   hts   = (const int*)d_in[10];
    float* out = (float*)d_out;

    char* base = (char*)d_ws;
    _Float16* WbP  = (_Float16*)base;  base += (size_t)KT_*NTIL_*64*8 * 2;      // 11.0 MB
    _Float16* WhP  = (_Float16*)base;  base += (size_t)48*48*64*8 * 2;          //  2.4 MB
    _Float16* WtP  = (_Float16*)base;  base += (size_t)48*48*64*8 * 2;          //  2.4 MB
    _Float16* seqP = (_Float16*)base;  base += (size_t)B_*32*48*64*8 * 2;       //  6.3 MB
    _Float16* ee   = (_Float16*)base;  base += (size_t)B_*E_*H_ * 2;            //  0.15 MB
    _Float16* ea   = (_Float16*)base;  base += (size_t)B_*E_*NH_*L_ * 2;        //  2.4 MB
    _Float16* ht   = (_Float16*)base;  base += (size_t)R_*L_ * 2;               //  4.5 MB
    _Float16* rs   = (_Float16*)base;  base += (size_t)R_*H_ * 2;               //  3.4 MB
    _Float16* zh   = (_Float16*)base;  base += (size_t)R_*H_ * 2;               //  3.4 MB
    _Float16* zt   = (_Float16*)base;  base += (size_t)R_*H_ * 2;               //  3.4 MB
    float*    part = (float*)base;                                              // 24.8 MB

    k_pack<<<dim3(PKB_ATT + PKB_WB + 2*PKB_W + PKB_SEQ + PKB_EMB), dim3(256), 0, stream>>>(
        att, Wb, Wh, Wt, seq, midx, mmask, ea, WbP, WhP, WtP, seqP, ee);

    k_ht_att<<<dim3(R_), dim3(128), 0, stream>>>(ea, hts, ht);

    k_rs_mfma<<<dim3(432), dim3(256), 0, stream>>>(ht, seqP, rs);

    k_z_mfma<<<dim3(840), dim3(256), 0, stream>>>(ee, rs, WhP, WtP, bh, bt, hts, zh, zt);

    k_logits_mfma  <<<dim3(216), dim3(512), 0, stream>>>(zh, zt, WbP, part);
    k_logits_reduce<<<dim3((R_*NL_ + 255)/256), dim3(256), 0, stream>>>(part, bb, out);
}

// Round 9
// 114.631 us; speedup vs baseline: 10.1272x; 1.0717x over previous
//
#include <hip/hip_runtime.h>
#include <math.h>

#define B_   4
#define L_   1024
#define H_   768
#define NH_  12
#define E_   24
#define M_   4
#define P_   552
#define NL_  97
#define H2_  1536          // 2*H
#define HB_  49152         // H*BLK
#define R_   2208          // B*P
#define NEG_ (-1e30f)

// logits MFMA tiling: BM=256 (4 waves x ms=4), 9 r-tiles, 48 K-chunks of 1024
#define RT2_  9
#define PR2_  2304         // RT2*256
#define S_    48
#define NTIL_ 7            // 112 padded cols / 16
#define KT_   1536         // HB/32 k-steps total

typedef _Float16 h2   __attribute__((ext_vector_type(2)));
typedef _Float16 f16x8 __attribute__((ext_vector_type(8)));
typedef float    f32x4 __attribute__((ext_vector_type(4)));

__device__ inline uint pkh(float lo, float hi) {      // fast RTZ pack
    union { __fp16 v __attribute__((ext_vector_type(2))); uint u; } c;
    c.v = __builtin_amdgcn_cvt_pkrtz(lo, hi);
    return c.u;
}
__device__ inline ushort h_rne(float x) {
    union { _Float16 h; ushort u; } c; c.h = (_Float16)x; return c.u;
}
__device__ inline uint h2_rne(float lo, float hi) {
    return (uint)h_rne(lo) | ((uint)h_rne(hi) << 16);
}

// ---------------- fused pack + ent_att + ent_emb ---------------------------
#define PKB_ATT 1152
#define PKB_WB  2688
#define PKB_W   576      // 48kt*48nt*64lane = 147456 = 576*256 EXACT
#define PKB_SEQ 1536
#define PKB_EMB 96
__global__ void k_pack(const float* __restrict__ att, const float* __restrict__ Wb,
                       const float* __restrict__ Wh, const float* __restrict__ Wt,
                       const float* __restrict__ seq,
                       const int* __restrict__ midx, const float* __restrict__ mmask,
                       _Float16* __restrict__ ea, _Float16* __restrict__ WbP,
                       _Float16* __restrict__ WhP, _Float16* __restrict__ WtP,
                       _Float16* __restrict__ seqP, _Float16* __restrict__ ee) {
    int bid = blockIdx.x;
    if (bid < PKB_ATT) {                    // entity_atts -> fp16 (float4 loads)
        int blk = bid;                      // (b*E+e)*NH + n
        int n  = blk % NH_;
        int be = blk / NH_;
        int b  = be / E_;
        int idx[M_]; float msk[M_]; float denom = 0.f;
#pragma unroll
        for (int m = 0; m < M_; ++m) { idx[m] = midx[be*M_+m]; msk[m] = mmask[be*M_+m]; denom += msk[m]; }
        float inv = 1.f / denom;
        const float* abase = att + (size_t)(b*NH_ + n) * L_ * L_;
        int l4 = threadIdx.x * 4;           // 256 threads x 4 = 1024
        float s0 = 0.f, s1 = 0.f, s2 = 0.f, s3 = 0.f;
#pragma unroll
        for (int m = 0; m < M_; ++m) {
            float4 a = *(const float4*)(abase + idx[m]*L_ + l4);
            s0 += msk[m]*a.x; s1 += msk[m]*a.y; s2 += msk[m]*a.z; s3 += msk[m]*a.w;
        }
        *(uint2*)(ea + (((size_t)(be*NH_ + n)) << 10) + l4) =
            make_uint2(pkh(s0*inv, s1*inv), pkh(s2*inv, s3*inv));
        return;
    }
    if (bid < PKB_ATT + PKB_WB) {           // Wb -> [kt][nt][lane][8]
        int t = (bid - PKB_ATT)*256 + threadIdx.x;
        int lane = t & 63;
        int nt   = (t >> 6) % NTIL_;
        int kt   = t / (NTIL_*64);
        int n = nt*16 + (lane & 15);
        int k = kt*32 + ((lane >> 4) << 3);
        uint w[4] = {0u,0u,0u,0u};
        if (n < NL_) {
            const float* src = Wb + (size_t)n*HB_ + k;
#pragma unroll
            for (int e = 0; e < 4; ++e) w[e] = h2_rne(src[2*e], src[2*e+1]);
        }
        *(uint4*)(WbP + (size_t)t*8) = make_uint4(w[0],w[1],w[2],w[3]);
        return;
    }
    if (bid < PKB_ATT + PKB_WB + 2*PKB_W) { // Wh / Wt -> [kt][nt][lane][8]
        int seg = bid - PKB_ATT - PKB_WB;
        const float* W = (seg < PKB_W) ? Wh : Wt;
        _Float16*   WP = (seg < PKB_W) ? WhP : WtP;
        int t = (seg % PKB_W)*256 + threadIdx.x;
        int lane = t & 63;
        int nt   = (t >> 6) % 48;
        int kt   = t / (48*64);
        int n = nt*16 + (lane & 15);
        int k = kt*32 + ((lane >> 4) << 3);
        const float* src = W + (size_t)n*H2_ + k;
        uint w[4];
#pragma unroll
        for (int e = 0; e < 4; ++e) w[e] = h2_rne(src[2*e], src[2*e+1]);
        *(uint4*)(WP + (size_t)t*8) = make_uint4(w[0],w[1],w[2],w[3]);
        return;
    }
    if (bid < PKB_ATT + PKB_WB + 2*PKB_W + PKB_SEQ) {   // seq -> per-b frag
        int t = (bid - PKB_ATT - PKB_WB - 2*PKB_W)*256 + threadIdx.x;
        int lane = t & 63;
        int rest = t >> 6;
        int nt = rest % 48; rest /= 48;
        int kt = rest % 32;
        int b  = rest / 32;
        int n = nt*16 + (lane & 15);
        int k = kt*32 + ((lane >> 4) << 3);
        const float* src = seq + ((size_t)(b*L_ + k))*H_ + n;
        uint w[4];
#pragma unroll
        for (int e = 0; e < 4; ++e) w[e] = h2_rne(src[(2*e)*H_], src[(2*e+1)*H_]);
        *(uint4*)(seqP + (size_t)t*8) = make_uint4(w[0],w[1],w[2],w[3]);
        return;
    }
    // ent_emb: logsumexp over mentions -> fp16
    int be = bid - (PKB_ATT + PKB_WB + 2*PKB_W + PKB_SEQ);
    int b  = be / E_;
    int idx[M_]; float msk[M_];
#pragma unroll
    for (int m = 0; m < M_; ++m) { idx[m] = midx[be*M_+m]; msk[m] = mmask[be*M_+m]; }
    for (int d = threadIdx.x; d < H_; d += 256) {
        float v[M_]; float mx = NEG_;
#pragma unroll
        for (int m = 0; m < M_; ++m) {
            v[m] = (msk[m] > 0.f) ? seq[(b*L_ + idx[m])*H_ + d] : NEG_;
            mx = fmaxf(mx, v[m]);
        }
        float s = 0.f;
#pragma unroll
        for (int m = 0; m < M_; ++m) s += expf(v[m] - mx);
        ee[be*H_ + d] = (_Float16)(mx + logf(s));
    }
}

// ---------------- K3: ht_att (128 threads, 16B loads) ----------------------
__global__ void k_ht_att(const _Float16* __restrict__ ea, const int* __restrict__ hts,
                         _Float16* __restrict__ ht) {
    __shared__ float red[2];
    int bp = blockIdx.x;            // b*P+p
    int b  = bp / P_;
    int h = hts[bp*2+0], t = hts[bp*2+1];
    const uint4* eh4 = (const uint4*)(ea + ((size_t)(b*E_ + h)*NH_ << 10));
    const uint4* et4 = (const uint4*)(ea + ((size_t)(b*E_ + t)*NH_ << 10));
    int lp = threadIdx.x;           // 0..127, each covers l = lp*8..+7
    float s[8] = {};
#pragma unroll
    for (int n = 0; n < NH_; ++n) {
        union { uint4 u; h2 v[4]; } A, C;
        A.u = eh4[n*128 + lp];
        C.u = et4[n*128 + lp];
#pragma unroll
        for (int q = 0; q < 4; ++q) {
            s[2*q]   += (float)A.v[q][0]*(float)C.v[q][0];
            s[2*q+1] += (float)A.v[q][1]*(float)C.v[q][1];
        }
    }
    float local = 0.f;
#pragma unroll
    for (int q = 0; q < 8; ++q) { s[q] *= (1.f/NH_); local += s[q]; }
#pragma unroll
    for (int o = 32; o > 0; o >>= 1) local += __shfl_down(local, o);
    int wid = threadIdx.x >> 6, lane = threadIdx.x & 63;
    if (lane == 0) red[wid] = local;
    __syncthreads();
    if (threadIdx.x == 0) red[0] = 1.f / (red[0] + red[1] + 1e-5f);
    __syncthreads();
    float inv = red[0];
    *(uint4*)(ht + ((size_t)bp << 10) + lp*8) =
        make_uint4(pkh(s[0]*inv, s[1]*inv), pkh(s[2]*inv, s[3]*inv),
                   pkh(s[4]*inv, s[5]*inv), pkh(s[6]*inv, s[7]*inv));
}

// ---------------- K4: rs = ht @ seq, BM=128 (ms=2), XCD-pinned b -----------
// flat grid 240: xcd=bid&7 -> b=xcd>>1; tile=(xcd&1)*30+(bid>>3): 5pt x 12nt
__launch_bounds__(256, 2)
__global__ void k_rs_mfma(const _Float16* __restrict__ ht, const _Float16* __restrict__ seqP,
                          _Float16* __restrict__ rs) {
    __shared__ _Float16 as[128*72];
    int bid = blockIdx.x;
    int xcd = bid & 7, jj0 = bid >> 3;   // jj0 0..29
    int b    = xcd >> 1;
    int tile = (xcd & 1)*30 + jj0;       // 0..59
    int p0   = (tile % 5) * 128;
    int nt0  = (tile / 5) * 4;
    int wave = threadIdx.x >> 6, lane = threadIdx.x & 63;

    const _Float16* srcp[4];
    int ldst[4];
#pragma unroll
    for (int i = 0; i < 4; ++i) {
        int t = threadIdx.x + i*256;
        int row = t >> 3, c8 = (t & 7)*8;
        int p = p0 + row;
        srcp[i] = (p < P_) ? ht + (((size_t)(b*P_ + p)) << 10) + c8 : nullptr;
        ldst[i] = row*72 + c8;
    }
    uint4 st[4];
#pragma unroll
    for (int i = 0; i < 4; ++i)
        st[i] = srcp[i] ? *(const uint4*)(srcp[i]) : make_uint4(0,0,0,0);

    f32x4 acc[2][4] = {};
    const _Float16* wbase = seqP + ((size_t)b*32*48 + nt0)*512 + lane*8;
    int rowbase = wave*32 + (lane & 15);
    int asub = (lane >> 4) << 3;

    for (int kc = 0; kc < 16; ++kc) {
        if (kc) __syncthreads();
#pragma unroll
        for (int i = 0; i < 4; ++i) *(uint4*)(as + ldst[i]) = st[i];
        __syncthreads();
        if (kc + 1 < 16) {
#pragma unroll
            for (int i = 0; i < 4; ++i)
                st[i] = srcp[i] ? *(const uint4*)(srcp[i] + (kc+1)*64) : make_uint4(0,0,0,0);
        }
#pragma unroll
        for (int kk = 0; kk < 2; ++kk) {
            int kt = kc*2 + kk;
            const _Float16* wp = wbase + (size_t)kt*(48*512);
            f16x8 bf[4];
#pragma unroll
            for (int jn = 0; jn < 4; ++jn) bf[jn] = *(const f16x8*)(wp + jn*512);
#pragma unroll
            for (int ms = 0; ms < 2; ++ms) {
                f16x8 af = *(const f16x8*)(as + (rowbase + ms*16)*72 + kk*32 + asub);
#pragma unroll
                for (int jn = 0; jn < 4; ++jn)
                    acc[ms][jn] = __builtin_amdgcn_mfma_f32_16x16x32_f16(af, bf[jn], acc[ms][jn], 0, 0, 0);
            }
        }
    }
    int crow = (lane >> 4) * 4;
    int ccol = lane & 15;
#pragma unroll
    for (int ms = 0; ms < 2; ++ms) {
#pragma unroll
        for (int jn = 0; jn < 4; ++jn) {
            int n = nt0*16 + jn*16 + ccol;
#pragma unroll
            for (int reg = 0; reg < 4; ++reg) {
                int p = p0 + wave*32 + ms*16 + crow + reg;
                if (p < P_) rs[(size_t)(b*P_ + p)*H_ + n] = (_Float16)acc[ms][jn][reg];
            }
        }
    }
}

// ---------------- K5: zh & zt, BM=128 (ms=2), XCD-pinned which -------------
// flat grid 432: xcd=bid&7 -> which=xcd>>2; tile=(xcd&3)*54+(bid>>3): 18rt x 12nt
__launch_bounds__(256, 2)
__global__ void k_z_mfma(const _Float16* __restrict__ ee, const _Float16* __restrict__ rs,
                         const _Float16* __restrict__ WhP, const _Float16* __restrict__ WtP,
                         const float* __restrict__ bh, const float* __restrict__ bt,
                         const int* __restrict__ hts,
                         _Float16* __restrict__ zh, _Float16* __restrict__ zt) {
    __shared__ _Float16 as[128*72];
    int bid = blockIdx.x;
    int xcd = bid & 7, jj0 = bid >> 3;   // jj0 0..53
    int which = xcd >> 2;
    int tile  = (xcd & 3)*54 + jj0;      // 0..215
    int r0  = (tile % 18) * 128;
    int nt0 = (tile / 18) * 4;
    const _Float16* WP   = which ? WtP : WhP;
    const float*    bias = which ? bt  : bh;
    _Float16*       out  = which ? zt  : zh;
    int wave = threadIdx.x >> 6, lane = threadIdx.x & 63;

    const _Float16* srcA[4];
    const _Float16* srcB[4];
    int ldst[4];
#pragma unroll
    for (int i = 0; i < 4; ++i) {
        int t = threadIdx.x + i*256;
        int row = t >> 3, c8 = (t & 7)*8;
        int r = r0 + row;
        if (r < R_) {
            int b = r / P_;
            int eidx = hts[r*2 + which];
            srcA[i] = ee + (size_t)(b*E_ + eidx)*H_ + c8;
            srcB[i] = rs + (size_t)r*H_ + c8;
        } else { srcA[i] = nullptr; srcB[i] = nullptr; }
        ldst[i] = row*72 + c8;
    }
    uint4 st[4];
#pragma unroll
    for (int i = 0; i < 4; ++i)
        st[i] = srcA[i] ? *(const uint4*)(srcA[i]) : make_uint4(0,0,0,0);

    f32x4 acc[2][4] = {};
    const _Float16* wbase = WP + (size_t)nt0*512 + lane*8;
    int rowbase = wave*32 + (lane & 15);
    int asub = (lane >> 4) << 3;

    for (int kc = 0; kc < 24; ++kc) {
        if (kc) __syncthreads();
#pragma unroll
        for (int i = 0; i < 4; ++i) *(uint4*)(as + ldst[i]) = st[i];
        __syncthreads();
        if (kc + 1 < 24) {
            int kn = kc + 1;
#pragma unroll
            for (int i = 0; i < 4; ++i) {
                const _Float16* s = (kn < 12) ? (srcA[i] ? srcA[i] + kn*64 : nullptr)
                                              : (srcB[i] ? srcB[i] + (kn-12)*64 : nullptr);
                st[i] = s ? *(const uint4*)s : make_uint4(0,0,0,0);
            }
        }
#pragma unroll
        for (int kk = 0; kk < 2; ++kk) {
            int kt = kc*2 + kk;
            const _Float16* wp = wbase + (size_t)kt*(48*512);
            f16x8 bf[4];
#pragma unroll
            for (int jn = 0; jn < 4; ++jn) bf[jn] = *(const f16x8*)(wp + jn*512);
#pragma unroll
            for (int ms = 0; ms < 2; ++ms) {
                f16x8 af = *(const f16x8*)(as + (rowbase + ms*16)*72 + kk*32 + asub);
#pragma unroll
                for (int jn = 0; jn < 4; ++jn)
                    acc[ms][jn] = __builtin_amdgcn_mfma_f32_16x16x32_f16(af, bf[jn], acc[ms][jn], 0, 0, 0);
            }
        }
    }
    int crow = (lane >> 4) * 4;
    int ccol = lane & 15;
#pragma unroll
    for (int ms = 0; ms < 2; ++ms) {
#pragma unroll
        for (int jn = 0; jn < 4; ++jn) {
            int n = nt0*16 + jn*16 + ccol;
            float bv = bias[n];
#pragma unroll
            for (int reg = 0; reg < 4; ++reg) {
                int r = r0 + wave*32 + ms*16 + crow + reg;
                if (r < R_) out[(size_t)r*H_ + n] = (_Float16)tanhf(acc[ms][jn][reg] + bv);
            }
        }
    }
}

// ---------------- K6: logits — BM=256, 4 waves, ms=4, S=48, fp16 part ------
// flat grid 432: xcd=bid&7 -> kc = xcd*6 + j/9 (6 kc per XCD, 1.4MB L2); rt=j%9
__launch_bounds__(256, 2)
__global__ void k_logits_mfma(const _Float16* __restrict__ zh, const _Float16* __restrict__ zt,
                              const _Float16* __restrict__ WbP, _Float16* __restrict__ part) {
    __shared__ _Float16 zhs[256*20];   // 10 KB (16 i-cols + pad)
    __shared__ _Float16 zts[256*72];   // 36.9 KB
    int bid = blockIdx.x;
    int xcd = bid & 7, j = bid >> 3;   // j 0..53
    int kc  = xcd*6 + j/9;             // 0..47
    int rt  = j % 9;
    int r0  = rt * 256;
    int g64 = (kc >> 2) * 64;          // zt col base (g block)
    int a0  = (kc & 3) * 16;           // zh col base within g

    for (int it = 0; it < 2; ++it) {
        int t = threadIdx.x + it*256;  // 0..511
        int row = t >> 1, i8 = (t & 1)*8;
        int r = r0 + row;
        uint4 w = make_uint4(0,0,0,0);
        if (r < R_) w = *(const uint4*)(zh + (size_t)r*H_ + g64 + a0 + i8);
        *(uint4*)(zhs + row*20 + i8) = w;
    }
    for (int it = 0; it < 8; ++it) {
        int t = threadIdx.x + it*256;  // 0..2047
        int row = t >> 3, j8 = (t & 7)*8;
        int r = r0 + row;
        uint4 w = make_uint4(0,0,0,0);
        if (r < R_) w = *(const uint4*)(zt + (size_t)r*H_ + g64 + j8);
        *(uint4*)(zts + row*72 + j8) = w;
    }
    __syncthreads();

    int wave = threadIdx.x >> 6, lane = threadIdx.x & 63;
    int rowA0 = wave*64 + (lane & 15);    // wave covers 64 rows (ms=4)
    int jsub  = (lane >> 4) * 8;

    f32x4 acc[4][NTIL_] = {};
    const _Float16* wb0 = WbP + (size_t)(kc*32) * (NTIL_*512) + lane*8;

    f16x8 bf[NTIL_];
#pragma unroll
    for (int nt = 0; nt < NTIL_; ++nt) bf[nt] = *(const f16x8*)(wb0 + nt*512);

    for (int ktl = 0; ktl < 32; ++ktl) {
        f16x8 bn[NTIL_];
        if (ktl + 1 < 32) {
            const _Float16* wp = wb0 + (size_t)(ktl+1) * (NTIL_*512);
#pragma unroll
            for (int nt = 0; nt < NTIL_; ++nt) bn[nt] = *(const f16x8*)(wp + nt*512);
        }
        int il = ktl >> 1;
        int jb = (ktl & 1) * 32 + jsub;
#pragma unroll
        for (int ms = 0; ms < 4; ++ms) {
            int row = rowA0 + ms*16;
            _Float16 hv = zhs[row*20 + il];
            h2 hb = {hv, hv};
            union { uint4 u; h2 v[4]; } T;
            T.u = *(const uint4*)(zts + row*72 + jb);
            union { h2 v[4]; f16x8 f; } A;
            A.v[0] = hb * T.v[0];
            A.v[1] = hb * T.v[1];
            A.v[2] = hb * T.v[2];
            A.v[3] = hb * T.v[3];
#pragma unroll
            for (int nt = 0; nt < NTIL_; ++nt)
                acc[ms][nt] = __builtin_amdgcn_mfma_f32_16x16x32_f16(A.f, bf[nt], acc[ms][nt], 0, 0, 0);
        }
        if (ktl + 1 < 32) {
#pragma unroll
            for (int nt = 0; nt < NTIL_; ++nt) bf[nt] = bn[nt];
        }
    }

    int crow0 = wave*64 + (lane >> 4) * 4;
    int ccol  = lane & 15;
#pragma unroll
    for (int ms = 0; ms < 4; ++ms) {
#pragma unroll
        for (int nt = 0; nt < NTIL_; ++nt) {
#pragma unroll
            for (int reg = 0; reg < 4; ++reg) {
                int rp = r0 + crow0 + ms*16 + reg;
                part[((size_t)kc*PR2_ + rp)*112 + nt*16 + ccol] = (_Float16)acc[ms][nt][reg];
            }
        }
    }
}

// ---------------- K7: reduce fp16 partials + bias --------------------------
__global__ void k_logits_reduce(const _Float16* __restrict__ part, const float* __restrict__ bb,
                                float* __restrict__ out) {
    int idx = blockIdx.x*256 + threadIdx.x;
    if (idx >= R_*NL_) return;
    int r = idx / NL_, n = idx - r*NL_;
    float s = bb[n];
#pragma unroll
    for (int kc = 0; kc < S_; ++kc) s += (float)part[((size_t)kc*PR2_ + r)*112 + n];
    out[idx] = s;
}

extern "C" void kernel_launch(void* const* d_in, const int* in_sizes, int n_in,
                              void* d_out, int out_size, void* d_ws, size_t ws_size,
                              hipStream_t stream) {
    const float* seq   = (const float*)d_in[0];
    const float* att   = (const float*)d_in[1];
    const float* mmask = (const float*)d_in[2];
    const float* Wh    = (const float*)d_in[3];
    const float* bh    = (const float*)d_in[4];
    const float* Wt    = (const float*)d_in[5];
    const float* bt    = (const float*)d_in[6];
    const float* Wb    = (const float*)d_in[7];
    const float* bb    = (const float*)d_in[8];
    const int*   midx  = (const int*)d_in[9];
    const int*   hts   = (const int*)d_in[10];
    float* out = (float*)d_out;

    char* base = (char*)d_ws;
    _Float16* WbP  = (_Float16*)base;  base += (size_t)KT_*NTIL_*64*8 * 2;      // 11.0 MB
    _Float16* WhP  = (_Float16*)base;  base += (size_t)48*48*64*8 * 2;          //  2.4 MB
    _Float16* WtP  = (_Float16*)base;  base += (size_t)48*48*64*8 * 2;          //  2.4 MB
    _Float16* seqP = (_Float16*)base;  base += (size_t)B_*32*48*64*8 * 2;       //  6.3 MB
    _Float16* ee   = (_Float16*)base;  base += (size_t)B_*E_*H_ * 2;            //  0.15 MB
    _Float16* ea   = (_Float16*)base;  base += (size_t)B_*E_*NH_*L_ * 2;        //  2.4 MB
    _Float16* ht   = (_Float16*)base;  base += (size_t)R_*L_ * 2;               //  4.5 MB
    _Float16* rs   = (_Float16*)base;  base += (size_t)R_*H_ * 2;               //  3.4 MB
    _Float16* zh   = (_Float16*)base;  base += (size_t)R_*H_ * 2;               //  3.4 MB
    _Float16* zt   = (_Float16*)base;  base += (size_t)R_*H_ * 2;               //  3.4 MB
    _Float16* part = (_Float16*)base;                                           // 24.8 MB

    k_pack<<<dim3(PKB_ATT + PKB_WB + 2*PKB_W + PKB_SEQ + PKB_EMB), dim3(256), 0, stream>>>(
        att, Wb, Wh, Wt, seq, midx, mmask, ea, WbP, WhP, WtP, seqP, ee);

    k_ht_att<<<dim3(R_), dim3(128), 0, stream>>>(ea, hts, ht);

    k_rs_mfma<<<dim3(240), dim3(256), 0, stream>>>(ht, seqP, rs);

    k_z_mfma<<<dim3(432), dim3(256), 0, stream>>>(ee, rs, WhP, WtP, bh, bt, hts, zh, zt);

    k_logits_mfma  <<<dim3(432), dim3(256), 0, stream>>>(zh, zt, WbP, part);
    k_logits_reduce<<<dim3((R_*NL_ + 255)/256), dim3(256), 0, stream>>>(part, bb, out);
}